// Round 7
// baseline (470.278 us; speedup 1.0000x reference)
//
#include <hip/hip_runtime.h>
#include <math.h>

#define HEADS 8
#define NEG 0.2f

typedef unsigned short ushort_t;
typedef __attribute__((ext_vector_type(8))) short short8;
typedef float f32x4 __attribute__((ext_vector_type(4)));

__device__ inline ushort_t f2bf(float f) {
  union { float f; unsigned u; } v; v.f = f;
  unsigned r = (v.u + 0x7FFF + ((v.u >> 16) & 1)) >> 16;  // RNE
  return (ushort_t)r;
}

__device__ inline float4 bf4(uint2 v) {
  union { unsigned u; float f; } a, b, c, d;
  a.u = v.x << 16; b.u = v.x & 0xffff0000u;
  c.u = v.y << 16; d.u = v.y & 0xffff0000u;
  return make_float4(a.f, b.f, c.f, d.f);
}

// fast ELU: exp(v)-1 via hw v_exp_f32; |abs err| ~1e-7, fine vs 1.7e-3 threshold
__device__ inline float elu_f(float v) {
  return (v > 0.f) ? v : (__expf(v) - 1.f);
}

// async global->LDS, 16B per lane; LDS dest is wave-uniform base + lane*16
#define GLDS16(gp, lp)                                                          \
  __builtin_amdgcn_global_load_lds(                                             \
      (const __attribute__((address_space(1))) void*)(gp),                      \
      (__attribute__((address_space(3))) void*)(lp), 16, 0, 0)

// ---- fused init: LDS-tiled W transpose (coalesced both ways) + zero + x->bf16 ----
// blocks 0..639: 32x32 transpose tiles (W1: 128 tiles, W2: 512 tiles)
// blocks 640.. : zero accum region + cast x to bf16
__global__ __launch_bounds__(256) void init_k(int* __restrict__ ws, int zero_words,
                                              const float* __restrict__ x,
                                              ushort_t* __restrict__ xb,
                                              const float* __restrict__ W1,
                                              ushort_t* __restrict__ w1t,
                                              const float* __restrict__ W2,
                                              ushort_t* __restrict__ w2t, int nx4) {
  __shared__ float tile[32][33];
  int blk = blockIdx.x;
  if (blk < 640) {
    const float* W; ushort_t* Wt; int K, N, tk, tn;
    if (blk < 128) { W = W1; Wt = w1t; K = 128; N = 1024; tk = blk >> 5; tn = blk & 31; }
    else { W = W2; Wt = w2t; K = 1024; N = 512; int t = blk - 128; tk = t >> 4; tn = t & 15; }
    int tx = threadIdx.x & 31, ty = threadIdx.x >> 5;  // 32 x 8
    int k0 = tk * 32, n0 = tn * 32;
#pragma unroll
    for (int r = 0; r < 4; r++)
      tile[ty + r * 8][tx] = W[(size_t)(k0 + ty + r * 8) * N + n0 + tx];  // coalesced read
    __syncthreads();
#pragma unroll
    for (int r = 0; r < 4; r++)
      Wt[(size_t)(n0 + ty + r * 8) * K + k0 + tx] = f2bf(tile[tx][ty + r * 8]);  // coalesced write
  } else {
    int i = (blk - 640) * 256 + threadIdx.x;
    if (i < zero_words) ws[i] = 0;
    if (i < nx4) {
      float4 v = ((const float4*)x)[i];
      ushort_t o[4] = {f2bf(v.x), f2bf(v.y), f2bf(v.z), f2bf(v.w)};
      *(uint2*)&xb[i * 4] = *(uint2*)o;
    }
  }
}

// -- edge prep + degree count + batch bounds fused (batch sorted; no atomics) --
__global__ void prep_k(const int* __restrict__ ei, int* __restrict__ src,
                       int* __restrict__ dst, int* __restrict__ deg,
                       const int* __restrict__ batch, int* __restrict__ bstart,
                       int* __restrict__ bend, int E, int Nn) {
  int i = blockIdx.x * blockDim.x + threadIdx.x;
  if (i < Nn) {
    int b = batch[i];
    if (i == 0 || batch[i - 1] != b) bstart[b] = i;
    if (i == Nn - 1 || batch[i + 1] != b) bend[b] = i + 1;
  }
  if (i >= E + Nn) return;
  int s, d;
  if (i < E) { s = ei[i]; d = ei[E + i]; }
  else       { s = d = i - E; }
  src[i] = s;
  dst[i] = d;
  atomicAdd(&deg[d], 1);
}

// single-block scan over N, 4 elems/thread (4096/chunk), wave-shuffle based
__global__ __launch_bounds__(1024) void scan_k(const int* __restrict__ deg,
                                               int* __restrict__ offs,
                                               int* __restrict__ cursor, int Nn) {
  __shared__ int wtot[16];
  __shared__ int wexcl[16];
  __shared__ int soff_s;
  int t = threadIdx.x;
  int lane = t & 63, w = t >> 6;
  if (t == 0) soff_s = 0;
  __syncthreads();
  for (int base = 0; base < Nn; base += 4096) {
    int idx = base + 4 * t;
    int4 v = make_int4(0, 0, 0, 0);
    if (idx + 3 < Nn) v = *(const int4*)&deg[idx];
    else {
      if (idx < Nn)     v.x = deg[idx];
      if (idx + 1 < Nn) v.y = deg[idx + 1];
      if (idx + 2 < Nn) v.z = deg[idx + 2];
      if (idx + 3 < Nn) v.w = deg[idx + 3];
    }
    int s1 = v.x, s2 = s1 + v.y, s3 = s2 + v.z, s4 = s3 + v.w;
    int sc = s4;  // wave-inclusive scan of per-thread totals
#pragma unroll
    for (int o = 1; o < 64; o <<= 1) {
      int x = __shfl_up(sc, o);
      if (lane >= o) sc += x;
    }
    if (lane == 63) wtot[w] = sc;
    __syncthreads();
    if (w == 0) {
      int tv = (lane < 16) ? wtot[lane] : 0;
      int ts = tv;
#pragma unroll
      for (int o = 1; o < 16; o <<= 1) {
        int x = __shfl_up(ts, o);
        if (lane >= o) ts += x;
      }
      if (lane < 16) wexcl[lane] = ts - tv;
      if (lane == 15) wtot[15] = ts;  // chunk total
    }
    __syncthreads();
    int excl = soff_s + wexcl[w] + (sc - s4);
    int o0 = excl, o1 = excl + s1, o2 = excl + s2, o3 = excl + s3;
    if (idx < Nn)     { offs[idx] = o0;     cursor[idx] = o0; }
    if (idx + 1 < Nn) { offs[idx + 1] = o1; cursor[idx + 1] = o1; }
    if (idx + 2 < Nn) { offs[idx + 2] = o2; cursor[idx + 2] = o2; }
    if (idx + 3 < Nn) { offs[idx + 3] = o3; cursor[idx + 3] = o3; }
    int chunk_total = wtot[15];
    __syncthreads();
    if (t == 0) soff_s += chunk_total;
    __syncthreads();
  }
  if (t == 0) offs[Nn] = soff_s;
}

// scatter src values directly into CSR slot order (no perm indirection)
__global__ void scatter_k(const int* __restrict__ src, const int* __restrict__ dst,
                          int* __restrict__ cursor, int* __restrict__ psrc, int Etot) {
  int i = blockIdx.x * blockDim.x + threadIdx.x;
  if (i >= Etot) return;
  int p = atomicAdd(&cursor[dst[i]], 1);
  psrc[p] = src[i];
}

// ------- bf16 MFMA GEMM + fused alpha epilogue: Cb[M,N](bf16) = A @ Bt^T -------
// 128x128 tile, 256 threads (4 waves 2x2), BK=64, dbuf 2-phase GLDS pipeline.
// Epilogue (R6-verified): C tile staged through LDS -> full-line uint4 stores;
// NO device atomics (block-exclusive (row,head) ownership, LDS cross-wave
// reduce + plain stores).
__global__ __launch_bounds__(256) void mfma_gemm_k(const ushort_t* __restrict__ A,
                                                   const ushort_t* __restrict__ Bt,
                                                   ushort_t* __restrict__ Cb,
                                                   const float* __restrict__ att_s,
                                                   const float* __restrict__ att_d,
                                                   float* __restrict__ asrc,
                                                   float* __restrict__ adst,
                                                   int M, int N, int K, int CSHIFT) {
  __shared__ __attribute__((aligned(16))) ushort_t lds[32768];  // 64KB, multi-use
  // K-loop: As buf b = lds[b*8192], Bs buf b = lds[16384 + b*8192]
  // epilogue: C tile [128][136] at lds[0]; alpha partials at lds[17472]
  int tid = threadIdx.x;
  int lane = tid & 63;
  int wave = tid >> 6;
  int wm = (wave >> 1) * 64, wn = (wave & 1) * 64;
  int bm = blockIdx.y * 128, bn = blockIdx.x * 128;
  int lrow = lane & 15, lq = lane >> 4;

  f32x4 acc[4][4];
#pragma unroll
  for (int i = 0; i < 4; i++)
#pragma unroll
    for (int j = 0; j < 4; j++) acc[i][j] = 0.f;

  int srow = lane >> 3;                    // row within chunk (== row&7)
  int scol = 8 * ((lane & 7) ^ srow);      // pre-swizzled column (elems)
  const ushort_t* pa[4];
  const ushort_t* pb[4];
  int lofs[4];
#pragma unroll
  for (int c = 0; c < 4; c++) {
    int row = wave * 32 + c * 8 + srow;
    int ga = min(bm + row, M - 1);         // clamp tail rows (dup of last row)
    pa[c] = &A[(size_t)ga * K + scol];
    pb[c] = &Bt[(size_t)(bn + row) * K + scol];
    lofs[c] = (wave * 4 + c) * 512;        // 1KiB chunks, wave-uniform base
  }

  auto stage = [&](int buf, int k0) {
#pragma unroll
    for (int c = 0; c < 4; c++) GLDS16(pa[c] + k0, &lds[buf * 8192 + lofs[c]]);
#pragma unroll
    for (int c = 0; c < 4; c++) GLDS16(pb[c] + k0, &lds[16384 + buf * 8192 + lofs[c]]);
  };

  auto compute = [&](int buf) {
    const ushort_t* Asb = &lds[buf * 8192];
    const ushort_t* Bsb = &lds[16384 + buf * 8192];
#pragma unroll
    for (int ks = 0; ks < 2; ks++) {
      short8 af[4], bfr[4];
#pragma unroll
      for (int t = 0; t < 4; t++) {
        int cbs = (ks * 64 + lq * 16) ^ ((lrow & 7) << 4);  // swizzled byte col
        af[t]  = *(const short8*)&Asb[(wm + t * 16 + lrow) * 64 + (cbs >> 1)];
        bfr[t] = *(const short8*)&Bsb[(wn + t * 16 + lrow) * 64 + (cbs >> 1)];
      }
#pragma unroll
      for (int i = 0; i < 4; i++)
#pragma unroll
        for (int j = 0; j < 4; j++)
          acc[i][j] = __builtin_amdgcn_mfma_f32_16x16x32_bf16(af[i], bfr[j], acc[i][j], 0, 0, 0);
    }
  };

  int NT = K >> 6;
  stage(0, 0);
  asm volatile("s_waitcnt vmcnt(0)" ::: "memory");
  __builtin_amdgcn_s_barrier();
  int cur = 0;
  for (int t = 0; t + 1 < NT; ++t) {
    stage(cur ^ 1, (t + 1) << 6);   // prefetch next K-tile; lands during compute
    compute(cur);
    asm volatile("s_waitcnt vmcnt(0)" ::: "memory");  // prefetch done (own loads)
    __builtin_amdgcn_s_barrier();   // publishes next buf + protects cur from overwrite
    cur ^= 1;
  }
  compute(cur);  // last tile, no prefetch

  __syncthreads();  // all waves done reading staging LDS -> safe to alias

  ushort_t* Cl = lds;                       // [128][136] bf16 (pad 136: 16B-aligned rows)
  float* pls = (float*)&lds[17472];         // [4 waves][64 rows] alpha-src partials
  float* pld = pls + 256;                   // [4][64] alpha-dst partials

  // ---- alpha partials (fp32, pre-rounding): 16-lane shfl reduce -> LDS ----
  {
    float avs[4], avd[4];
#pragma unroll
    for (int j = 0; j < 4; j++) {
      int col = bn + wn + j * 16 + lrow;  // att [H][N/H] flat == column index
      avs[j] = att_s[col];
      avd[j] = att_d[col];
    }
#pragma unroll
    for (int i = 0; i < 4; i++) {
#pragma unroll
      for (int r = 0; r < 4; r++) {
        float ps = 0.f, pd = 0.f;
#pragma unroll
        for (int j = 0; j < 4; j++) {
          float v = acc[i][j][r];
          ps += v * avs[j];
          pd += v * avd[j];
        }
#pragma unroll
        for (int o = 1; o < 16; o <<= 1) {
          ps += __shfl_xor(ps, o);
          pd += __shfl_xor(pd, o);
        }
        if (lrow == 0) {
          int rr = i * 16 + lq * 4 + r;   // 0..63 within wave tile
          pls[wave * 64 + rr] = ps;
          pld[wave * 64 + rr] = pd;
        }
      }
    }
  }

  // ---- C tile -> LDS (bf16) ----
#pragma unroll
  for (int i = 0; i < 4; i++) {
#pragma unroll
    for (int j = 0; j < 4; j++) {
      int col = wn + j * 16 + lrow;
#pragma unroll
      for (int r = 0; r < 4; r++) {
        int row = wm + i * 16 + lq * 4 + r;  // C/D: col=lane&15, row=(lane>>4)*4+reg
        Cl[row * 136 + col] = f2bf(acc[i][j][r]);
      }
    }
  }
  __syncthreads();

  // ---- coalesced C store: full 64B-line writes (16 rows x 16 uint4 per pass) ----
#pragma unroll
  for (int p = 0; p < 8; p++) {
    int row = p * 16 + (tid >> 4);
    int col8 = (tid & 15) * 8;
    if (bm + row < M)
      *(uint4*)&Cb[(size_t)(bm + row) * N + bn + col8] = *(const uint4*)&Cl[row * 136 + col8];
  }

  // ---- alpha store: plain stores, block-exclusive (row,head) ownership ----
  {
    int r = tid & 127, half = tid >> 7;     // 256 threads: 128 rows x {src,dst}
    if (bm + r < M) {
      const float* P = half ? pld : pls;
      float* O = half ? adst : asrc;
      int w0 = (r >> 6) * 2, idx = r & 63;
      float va = P[w0 * 64 + idx];          // wn=0 wave half (cols bn..bn+63)
      float vb = P[(w0 + 1) * 64 + idx];    // wn=64 wave half (cols bn+64..bn+127)
      int h0 = bn >> CSHIFT, h1 = (bn + 64) >> CSHIFT;
      size_t base = (size_t)(bm + r) * HEADS;
      if (h0 == h1) O[base + h0] = va + vb;           // layer1: head = 128 cols
      else { O[base + h0] = va; O[base + h1] = vb; }  // layer2: head = 64 cols
    }
  }
}

// ---- CSR aggregation: barrier-free, LDS-free, DEPTH-2 pipelined uint2 gathers ----
// NSPLIT blocks per node; block handles CPB = F/NSPLIT channels with BT = CPB/4
// threads (4 consecutive channels each). Batch k+1's 16 loads are issued BEFORE
// consuming batch k (~32 loads in flight/wave; wave count unchanged - R14).
// POOL variant (layer 2): skip the g write entirely, atomicAdd post-ELU values
// into 4-way-split pool sums [4][16][512] (split by n&3 cuts per-address
// contention to ~156) - fuses pool_k and kills 40MB of g traffic + a launch.
template <int F, int CSHIFT, int BT, int NSPLIT, typename OT, bool POOL>
__global__ __launch_bounds__(BT) void aggregate_k(const ushort_t* __restrict__ hb,
                                                  const float* __restrict__ asrc,
                                                  const float* __restrict__ adst,
                                                  const int* __restrict__ offs,
                                                  const int* __restrict__ psrc,
                                                  const float* __restrict__ bias,
                                                  OT* __restrict__ out,
                                                  const int* __restrict__ batch,
                                                  float* __restrict__ sums) {
  constexpr int CPB = F / NSPLIT;
  static_assert(CPB == 4 * BT, "CPB/thread mismatch");
  int nb = blockIdx.x;
  int n = nb / NSPLIT;
  int coff = (nb - n * NSPLIT) * CPB;
  int t = threadIdx.x;
  int c0 = coff + 4 * t;
  int hh = c0 >> CSHIFT;
  float adn = adst[n * HEADS + hh];
  int e0 = offs[n], e1 = offs[n + 1];
  float4 acc = make_float4(0.f, 0.f, 0.f, 0.f);
  float wsum = 0.f;

  int i = e0;
  uint2 rA[8];
  float avA[8];
  bool haveA = (i + 8 <= e1);
  if (haveA) {
    int sA[8];
#pragma unroll
    for (int u = 0; u < 8; u++) sA[u] = psrc[i + u];
#pragma unroll
    for (int u = 0; u < 8; u++) rA[u] = *(const uint2*)&hb[(size_t)sA[u] * F + c0];
#pragma unroll
    for (int u = 0; u < 8; u++) avA[u] = asrc[sA[u] * HEADS + hh];
  }
  while (i + 16 <= e1) {
    // issue batch B (16 loads) before consuming batch A
    int sB[8];
    uint2 rB[8];
    float avB[8];
#pragma unroll
    for (int u = 0; u < 8; u++) sB[u] = psrc[i + 8 + u];
#pragma unroll
    for (int u = 0; u < 8; u++) rB[u] = *(const uint2*)&hb[(size_t)sB[u] * F + c0];
#pragma unroll
    for (int u = 0; u < 8; u++) avB[u] = asrc[sB[u] * HEADS + hh];
#pragma unroll
    for (int u = 0; u < 8; u++) {
      float v = avA[u] + adn;
      v = (v > 0.f) ? v : NEG * v;  // leaky_relu(0.2)
      float w = __expf(v);          // hw v_exp_f32; shift-invariant softmax
      float4 f = bf4(rA[u]);
      wsum += w;
      acc.x += w * f.x;
      acc.y += w * f.y;
      acc.z += w * f.z;
      acc.w += w * f.w;
    }
    i += 8;
#pragma unroll
    for (int u = 0; u < 8; u++) { rA[u] = rB[u]; avA[u] = avB[u]; }
  }
  if (haveA) {
#pragma unroll
    for (int u = 0; u < 8; u++) {
      float v = avA[u] + adn;
      v = (v > 0.f) ? v : NEG * v;
      float w = __expf(v);
      float4 f = bf4(rA[u]);
      wsum += w;
      acc.x += w * f.x;
      acc.y += w * f.y;
      acc.z += w * f.z;
      acc.w += w * f.w;
    }
    i += 8;
  }
  for (; i < e1; i++) {
    int ss = psrc[i];
    float v = asrc[ss * HEADS + hh] + adn;
    v = (v > 0.f) ? v : NEG * v;
    float w = __expf(v);
    float4 f = bf4(*(const uint2*)&hb[(size_t)ss * F + c0]);
    wsum += w;
    acc.x += w * f.x; acc.y += w * f.y;
    acc.z += w * f.z; acc.w += w * f.w;
  }

  float inv = 1.f / wsum;
  float v0 = elu_f(acc.x * inv + bias[c0]);
  float v1 = elu_f(acc.y * inv + bias[c0 + 1]);
  float v2 = elu_f(acc.z * inv + bias[c0 + 2]);
  float v3 = elu_f(acc.w * inv + bias[c0 + 3]);
  if constexpr (POOL) {
    int b = batch[n];
    float* S = sums + ((n & 3) << 13) + (b << 9) + c0;
    atomicAdd(&S[0], v0);
    atomicAdd(&S[1], v1);
    atomicAdd(&S[2], v2);
    atomicAdd(&S[3], v3);
  } else if constexpr (sizeof(OT) == 2) {
    unsigned p0 = (unsigned)f2bf(v0) | ((unsigned)f2bf(v1) << 16);
    unsigned p1 = (unsigned)f2bf(v2) | ((unsigned)f2bf(v3) << 16);
    *(uint2*)&((ushort_t*)out)[(size_t)n * F + c0] = make_uint2(p0, p1);
  } else {
    *(float4*)&((float*)out)[(size_t)n * F + c0] = make_float4(v0, v1, v2, v3);
  }
}

// ---------------- mean + fc1(elu) + fc2, one block ----------------
// sums is 4-way split [4][16][512] (agg2 atomic pool) -> sum partials here.
__global__ __launch_bounds__(512) void mlp_k(const float* __restrict__ sums,
                                             const int* __restrict__ bstart,
                                             const int* __restrict__ bend,
                                             const float* __restrict__ w1,
                                             const float* __restrict__ b1,
                                             const float* __restrict__ w2,
                                             const float* __restrict__ b2,
                                             float* __restrict__ out) {
  __shared__ float gm[16 * 512];
  __shared__ float t1[16 * 32];
  int t = threadIdx.x;
  for (int i = t; i < 16 * 512; i += 512) {
    int b = i >> 9;
    float c = (float)(bend[b] - bstart[b]);
    float s = sums[i] + sums[i + 8192] + sums[i + 16384] + sums[i + 24576];
    gm[i] = s / fmaxf(c, 1.f);
  }
  __syncthreads();
  {
    int b = t >> 5, j = t & 31;
    float s = b1[j];
    for (int k = 0; k < 512; k++) s += gm[(b << 9) + k] * w1[k * 32 + j];
    t1[t] = elu_f(s);
  }
  __syncthreads();
  if (t < 160) {
    int b = t / 10, j = t - b * 10;
    float s = b2[j];
#pragma unroll
    for (int k = 0; k < 32; k++) s += t1[b * 32 + k] * w2[k * 10 + j];
    out[t] = s;
  }
}

extern "C" void kernel_launch(void* const* d_in, const int* in_sizes, int n_in,
                              void* d_out, int out_size, void* d_ws, size_t ws_size,
                              hipStream_t stream) {
  const float* x   = (const float*)d_in[0];
  const int*   ei  = (const int*)d_in[1];
  const int* batch = (const int*)d_in[2];
  const float* W1  = (const float*)d_in[3];
  const float* as1 = (const float*)d_in[4];
  const float* ad1 = (const float*)d_in[5];
  const float* b1  = (const float*)d_in[6];
  const float* W2  = (const float*)d_in[7];
  const float* as2 = (const float*)d_in[8];
  const float* ad2 = (const float*)d_in[9];
  const float* b2  = (const float*)d_in[10];
  const float* f1w = (const float*)d_in[11];
  const float* f1b = (const float*)d_in[12];
  const float* f2w = (const float*)d_in[13];
  const float* f2b = (const float*)d_in[14];
  float* out = (float*)d_out;

  const int Nn = in_sizes[2];      // 10000
  const int E = in_sizes[1] / 2;   // 160000
  const int Etot = E + Nn;         // self loops appended

  // ---- workspace layout (4B words, 64-word aligned) ----
  size_t off = 0;
  auto alloc = [&](size_t elems) { size_t o = off; off += (elems + 63) & ~(size_t)63; return o; };
  int* wsi = (int*)d_ws;
  float* wsf = (float*)d_ws;

  size_t o_deg  = alloc(Nn);
  size_t o_pool = alloc(4 * 16 * 512);   // 4-way split pool sums (agg2 atomics)
  size_t zero_words = off;               // only deg+pool accumulate -> zero each call
  size_t o_as1  = alloc((size_t)Nn * 8); // plain-stored by GEMM epilogue
  size_t o_ad1  = alloc((size_t)Nn * 8);
  size_t o_as2  = alloc((size_t)Nn * 8);
  size_t o_ad2  = alloc((size_t)Nn * 8);
  size_t o_bst  = alloc(64);
  size_t o_ben  = alloc(64);
  size_t o_offs = alloc(Nn + 1);
  size_t o_cur  = alloc(Nn);
  size_t o_src  = alloc(Etot);
  size_t o_dst  = alloc(Etot);
  size_t o_psrc = alloc(Etot);
  size_t o_xb   = alloc((size_t)Nn * 128 / 2);   // x bf16  [N,128]
  size_t o_w1t  = alloc(1024 * 128 / 2);         // W1^T bf16 [1024,128]
  size_t o_w2t  = alloc(512 * 1024 / 2);         // W2^T bf16 [512,1024]
  size_t o_h    = alloc((size_t)Nn * 1024 / 2);  // h bf16 [N,1024] (layer2 uses first half)
  size_t o_g    = alloc((size_t)Nn * 1024 / 2);  // g1 bf16 [N,1024]

  ushort_t* xb  = (ushort_t*)(wsi + o_xb);
  ushort_t* w1t = (ushort_t*)(wsi + o_w1t);
  ushort_t* w2t = (ushort_t*)(wsi + o_w2t);
  ushort_t* hb  = (ushort_t*)(wsi + o_h);
  ushort_t* g1b = (ushort_t*)(wsi + o_g);

  int eb = (Etot + 255) / 256;

  int nx4 = Nn * 128 / 4;
  int ep_work = (int)((zero_words > (size_t)nx4 ? zero_words : (size_t)nx4));
  int init_blocks = 640 + (ep_work + 255) / 256;
  init_k<<<init_blocks, 256, 0, stream>>>(wsi, (int)zero_words, x, xb,
                                          W1, w1t, W2, w2t, nx4);
  prep_k<<<eb, 256, 0, stream>>>(ei, wsi + o_src, wsi + o_dst, wsi + o_deg,
                                 batch, wsi + o_bst, wsi + o_ben, E, Nn);
  scan_k<<<1, 1024, 0, stream>>>(wsi + o_deg, wsi + o_offs, wsi + o_cur, Nn);
  scatter_k<<<eb, 256, 0, stream>>>(wsi + o_src, wsi + o_dst, wsi + o_cur,
                                    wsi + o_psrc, Etot);

  // ---- layer 1: 128 -> 8x128 ----
  mfma_gemm_k<<<dim3(1024 / 128, (Nn + 127) / 128), 256, 0, stream>>>(
      xb, w1t, hb, as1, ad1, wsf + o_as1, wsf + o_ad1, Nn, 1024, 128, 7);
  aggregate_k<1024, 7, 128, 2, ushort_t, false><<<Nn * 2, 128, 0, stream>>>(
      hb, wsf + o_as1, wsf + o_ad1, wsi + o_offs, wsi + o_psrc, b1, g1b,
      nullptr, nullptr);

  // ---- layer 2: 1024 -> 8x64 (pool fused via split atomics) ----
  mfma_gemm_k<<<dim3(512 / 128, (Nn + 127) / 128), 256, 0, stream>>>(
      g1b, w2t, hb, as2, ad2, wsf + o_as2, wsf + o_ad2, Nn, 512, 1024, 6);
  aggregate_k<512, 6, 64, 2, float, true><<<Nn * 2, 64, 0, stream>>>(
      hb, wsf + o_as2, wsf + o_ad2, wsi + o_offs, wsi + o_psrc, b2,
      (float*)nullptr, batch, wsf + o_pool);

  // ---- MLP (mean folded in) ----
  mlp_k<<<1, 512, 0, stream>>>(wsf + o_pool, wsi + o_bst, wsi + o_ben, f1w, f1b, f2w, f2b, out);
}

// Round 8
// 256.334 us; speedup vs baseline: 1.8346x; 1.8346x over previous
//
#include <hip/hip_runtime.h>
#include <math.h>

#define HEADS 8
#define NEG 0.2f

typedef unsigned short ushort_t;
typedef __attribute__((ext_vector_type(8))) short short8;
typedef float f32x4 __attribute__((ext_vector_type(4)));

__device__ inline ushort_t f2bf(float f) {
  union { float f; unsigned u; } v; v.f = f;
  unsigned r = (v.u + 0x7FFF + ((v.u >> 16) & 1)) >> 16;  // RNE
  return (ushort_t)r;
}

__device__ inline float4 bf4(uint2 v) {
  union { unsigned u; float f; } a, b, c, d;
  a.u = v.x << 16; b.u = v.x & 0xffff0000u;
  c.u = v.y << 16; d.u = v.y & 0xffff0000u;
  return make_float4(a.f, b.f, c.f, d.f);
}

// fast ELU: exp(v)-1 via hw v_exp_f32; |abs err| ~1e-7, fine vs 1.7e-3 threshold
__device__ inline float elu_f(float v) {
  return (v > 0.f) ? v : (__expf(v) - 1.f);
}

// async global->LDS, 16B per lane; LDS dest is wave-uniform base + lane*16
#define GLDS16(gp, lp)                                                          \
  __builtin_amdgcn_global_load_lds(                                             \
      (const __attribute__((address_space(1))) void*)(gp),                      \
      (__attribute__((address_space(3))) void*)(lp), 16, 0, 0)

// ---- fused init: LDS-tiled W transpose (coalesced both ways) + zero + x->bf16 ----
// blocks 0..639: 32x32 transpose tiles (W1: 128 tiles, W2: 512 tiles)
// blocks 640.. : zero accum region + cast x to bf16
__global__ __launch_bounds__(256) void init_k(int* __restrict__ ws, int zero_words,
                                              const float* __restrict__ x,
                                              ushort_t* __restrict__ xb,
                                              const float* __restrict__ W1,
                                              ushort_t* __restrict__ w1t,
                                              const float* __restrict__ W2,
                                              ushort_t* __restrict__ w2t, int nx4) {
  __shared__ float tile[32][33];
  int blk = blockIdx.x;
  if (blk < 640) {
    const float* W; ushort_t* Wt; int K, N, tk, tn;
    if (blk < 128) { W = W1; Wt = w1t; K = 128; N = 1024; tk = blk >> 5; tn = blk & 31; }
    else { W = W2; Wt = w2t; K = 1024; N = 512; int t = blk - 128; tk = t >> 4; tn = t & 15; }
    int tx = threadIdx.x & 31, ty = threadIdx.x >> 5;  // 32 x 8
    int k0 = tk * 32, n0 = tn * 32;
#pragma unroll
    for (int r = 0; r < 4; r++)
      tile[ty + r * 8][tx] = W[(size_t)(k0 + ty + r * 8) * N + n0 + tx];  // coalesced read
    __syncthreads();
#pragma unroll
    for (int r = 0; r < 4; r++)
      Wt[(size_t)(n0 + ty + r * 8) * K + k0 + tx] = f2bf(tile[tx][ty + r * 8]);  // coalesced write
  } else {
    int i = (blk - 640) * 256 + threadIdx.x;
    if (i < zero_words) ws[i] = 0;
    if (i < nx4) {
      float4 v = ((const float4*)x)[i];
      ushort_t o[4] = {f2bf(v.x), f2bf(v.y), f2bf(v.z), f2bf(v.w)};
      *(uint2*)&xb[i * 4] = *(uint2*)o;
    }
  }
}

// -- edge prep + degree count + batch bounds fused (batch sorted; no atomics) --
__global__ void prep_k(const int* __restrict__ ei, int* __restrict__ src,
                       int* __restrict__ dst, int* __restrict__ deg,
                       const int* __restrict__ batch, int* __restrict__ bstart,
                       int* __restrict__ bend, int E, int Nn) {
  int i = blockIdx.x * blockDim.x + threadIdx.x;
  if (i < Nn) {
    int b = batch[i];
    if (i == 0 || batch[i - 1] != b) bstart[b] = i;
    if (i == Nn - 1 || batch[i + 1] != b) bend[b] = i + 1;
  }
  if (i >= E + Nn) return;
  int s, d;
  if (i < E) { s = ei[i]; d = ei[E + i]; }
  else       { s = d = i - E; }
  src[i] = s;
  dst[i] = d;
  atomicAdd(&deg[d], 1);
}

// single-block scan over N, 4 elems/thread (4096/chunk), wave-shuffle based
__global__ __launch_bounds__(1024) void scan_k(const int* __restrict__ deg,
                                               int* __restrict__ offs,
                                               int* __restrict__ cursor, int Nn) {
  __shared__ int wtot[16];
  __shared__ int wexcl[16];
  __shared__ int soff_s;
  int t = threadIdx.x;
  int lane = t & 63, w = t >> 6;
  if (t == 0) soff_s = 0;
  __syncthreads();
  for (int base = 0; base < Nn; base += 4096) {
    int idx = base + 4 * t;
    int4 v = make_int4(0, 0, 0, 0);
    if (idx + 3 < Nn) v = *(const int4*)&deg[idx];
    else {
      if (idx < Nn)     v.x = deg[idx];
      if (idx + 1 < Nn) v.y = deg[idx + 1];
      if (idx + 2 < Nn) v.z = deg[idx + 2];
      if (idx + 3 < Nn) v.w = deg[idx + 3];
    }
    int s1 = v.x, s2 = s1 + v.y, s3 = s2 + v.z, s4 = s3 + v.w;
    int sc = s4;  // wave-inclusive scan of per-thread totals
#pragma unroll
    for (int o = 1; o < 64; o <<= 1) {
      int x = __shfl_up(sc, o);
      if (lane >= o) sc += x;
    }
    if (lane == 63) wtot[w] = sc;
    __syncthreads();
    if (w == 0) {
      int tv = (lane < 16) ? wtot[lane] : 0;
      int ts = tv;
#pragma unroll
      for (int o = 1; o < 16; o <<= 1) {
        int x = __shfl_up(ts, o);
        if (lane >= o) ts += x;
      }
      if (lane < 16) wexcl[lane] = ts - tv;
      if (lane == 15) wtot[15] = ts;  // chunk total
    }
    __syncthreads();
    int excl = soff_s + wexcl[w] + (sc - s4);
    int o0 = excl, o1 = excl + s1, o2 = excl + s2, o3 = excl + s3;
    if (idx < Nn)     { offs[idx] = o0;     cursor[idx] = o0; }
    if (idx + 1 < Nn) { offs[idx + 1] = o1; cursor[idx + 1] = o1; }
    if (idx + 2 < Nn) { offs[idx + 2] = o2; cursor[idx + 2] = o2; }
    if (idx + 3 < Nn) { offs[idx + 3] = o3; cursor[idx + 3] = o3; }
    int chunk_total = wtot[15];
    __syncthreads();
    if (t == 0) soff_s += chunk_total;
    __syncthreads();
  }
  if (t == 0) offs[Nn] = soff_s;
}

// scatter src values directly into CSR slot order (no perm indirection)
__global__ void scatter_k(const int* __restrict__ src, const int* __restrict__ dst,
                          int* __restrict__ cursor, int* __restrict__ psrc, int Etot) {
  int i = blockIdx.x * blockDim.x + threadIdx.x;
  if (i >= Etot) return;
  int p = atomicAdd(&cursor[dst[i]], 1);
  psrc[p] = src[i];
}

// ------- bf16 MFMA GEMM + fused alpha epilogue: Cb[M,N](bf16) = A @ Bt^T -------
// 128x128 tile, 256 threads (4 waves 2x2), BK=64, dbuf 2-phase GLDS pipeline.
// Epilogue (R6-verified): C tile staged through LDS -> full-line uint4 stores;
// NO device atomics (block-exclusive (row,head) ownership, LDS cross-wave
// reduce + plain stores).
__global__ __launch_bounds__(256) void mfma_gemm_k(const ushort_t* __restrict__ A,
                                                   const ushort_t* __restrict__ Bt,
                                                   ushort_t* __restrict__ Cb,
                                                   const float* __restrict__ att_s,
                                                   const float* __restrict__ att_d,
                                                   float* __restrict__ asrc,
                                                   float* __restrict__ adst,
                                                   int M, int N, int K, int CSHIFT) {
  __shared__ __attribute__((aligned(16))) ushort_t lds[32768];  // 64KB, multi-use
  // K-loop: As buf b = lds[b*8192], Bs buf b = lds[16384 + b*8192]
  // epilogue: C tile [128][136] at lds[0]; alpha partials at lds[17472]
  int tid = threadIdx.x;
  int lane = tid & 63;
  int wave = tid >> 6;
  int wm = (wave >> 1) * 64, wn = (wave & 1) * 64;
  int bm = blockIdx.y * 128, bn = blockIdx.x * 128;
  int lrow = lane & 15, lq = lane >> 4;

  f32x4 acc[4][4];
#pragma unroll
  for (int i = 0; i < 4; i++)
#pragma unroll
    for (int j = 0; j < 4; j++) acc[i][j] = 0.f;

  int srow = lane >> 3;                    // row within chunk (== row&7)
  int scol = 8 * ((lane & 7) ^ srow);      // pre-swizzled column (elems)
  const ushort_t* pa[4];
  const ushort_t* pb[4];
  int lofs[4];
#pragma unroll
  for (int c = 0; c < 4; c++) {
    int row = wave * 32 + c * 8 + srow;
    int ga = min(bm + row, M - 1);         // clamp tail rows (dup of last row)
    pa[c] = &A[(size_t)ga * K + scol];
    pb[c] = &Bt[(size_t)(bn + row) * K + scol];
    lofs[c] = (wave * 4 + c) * 512;        // 1KiB chunks, wave-uniform base
  }

  auto stage = [&](int buf, int k0) {
#pragma unroll
    for (int c = 0; c < 4; c++) GLDS16(pa[c] + k0, &lds[buf * 8192 + lofs[c]]);
#pragma unroll
    for (int c = 0; c < 4; c++) GLDS16(pb[c] + k0, &lds[16384 + buf * 8192 + lofs[c]]);
  };

  auto compute = [&](int buf) {
    const ushort_t* Asb = &lds[buf * 8192];
    const ushort_t* Bsb = &lds[16384 + buf * 8192];
#pragma unroll
    for (int ks = 0; ks < 2; ks++) {
      short8 af[4], bfr[4];
#pragma unroll
      for (int t = 0; t < 4; t++) {
        int cbs = (ks * 64 + lq * 16) ^ ((lrow & 7) << 4);  // swizzled byte col
        af[t]  = *(const short8*)&Asb[(wm + t * 16 + lrow) * 64 + (cbs >> 1)];
        bfr[t] = *(const short8*)&Bsb[(wn + t * 16 + lrow) * 64 + (cbs >> 1)];
      }
#pragma unroll
      for (int i = 0; i < 4; i++)
#pragma unroll
        for (int j = 0; j < 4; j++)
          acc[i][j] = __builtin_amdgcn_mfma_f32_16x16x32_bf16(af[i], bfr[j], acc[i][j], 0, 0, 0);
    }
  };

  int NT = K >> 6;
  stage(0, 0);
  asm volatile("s_waitcnt vmcnt(0)" ::: "memory");
  __builtin_amdgcn_s_barrier();
  int cur = 0;
  for (int t = 0; t + 1 < NT; ++t) {
    stage(cur ^ 1, (t + 1) << 6);   // prefetch next K-tile; lands during compute
    compute(cur);
    asm volatile("s_waitcnt vmcnt(0)" ::: "memory");  // prefetch done (own loads)
    __builtin_amdgcn_s_barrier();   // publishes next buf + protects cur from overwrite
    cur ^= 1;
  }
  compute(cur);  // last tile, no prefetch

  __syncthreads();  // all waves done reading staging LDS -> safe to alias

  ushort_t* Cl = lds;                       // [128][136] bf16 (pad 136: 16B-aligned rows)
  float* pls = (float*)&lds[17472];         // [4 waves][64 rows] alpha-src partials
  float* pld = pls + 256;                   // [4][64] alpha-dst partials

  // ---- alpha partials (fp32, pre-rounding): 16-lane shfl reduce -> LDS ----
  {
    float avs[4], avd[4];
#pragma unroll
    for (int j = 0; j < 4; j++) {
      int col = bn + wn + j * 16 + lrow;  // att [H][N/H] flat == column index
      avs[j] = att_s[col];
      avd[j] = att_d[col];
    }
#pragma unroll
    for (int i = 0; i < 4; i++) {
#pragma unroll
      for (int r = 0; r < 4; r++) {
        float ps = 0.f, pd = 0.f;
#pragma unroll
        for (int j = 0; j < 4; j++) {
          float v = acc[i][j][r];
          ps += v * avs[j];
          pd += v * avd[j];
        }
#pragma unroll
        for (int o = 1; o < 16; o <<= 1) {
          ps += __shfl_xor(ps, o);
          pd += __shfl_xor(pd, o);
        }
        if (lrow == 0) {
          int rr = i * 16 + lq * 4 + r;   // 0..63 within wave tile
          pls[wave * 64 + rr] = ps;
          pld[wave * 64 + rr] = pd;
        }
      }
    }
  }

  // ---- C tile -> LDS (bf16) ----
#pragma unroll
  for (int i = 0; i < 4; i++) {
#pragma unroll
    for (int j = 0; j < 4; j++) {
      int col = wn + j * 16 + lrow;
#pragma unroll
      for (int r = 0; r < 4; r++) {
        int row = wm + i * 16 + lq * 4 + r;  // C/D: col=lane&15, row=(lane>>4)*4+reg
        Cl[row * 136 + col] = f2bf(acc[i][j][r]);
      }
    }
  }
  __syncthreads();

  // ---- coalesced C store: full 64B-line writes (16 rows x 16 uint4 per pass) ----
#pragma unroll
  for (int p = 0; p < 8; p++) {
    int row = p * 16 + (tid >> 4);
    int col8 = (tid & 15) * 8;
    if (bm + row < M)
      *(uint4*)&Cb[(size_t)(bm + row) * N + bn + col8] = *(const uint4*)&Cl[row * 136 + col8];
  }

  // ---- alpha store: plain stores, block-exclusive (row,head) ownership ----
  {
    int r = tid & 127, half = tid >> 7;     // 256 threads: 128 rows x {src,dst}
    if (bm + r < M) {
      const float* P = half ? pld : pls;
      float* O = half ? adst : asrc;
      int w0 = (r >> 6) * 2, idx = r & 63;
      float va = P[w0 * 64 + idx];          // wn=0 wave half (cols bn..bn+63)
      float vb = P[(w0 + 1) * 64 + idx];    // wn=64 wave half (cols bn+64..bn+127)
      int h0 = bn >> CSHIFT, h1 = (bn + 64) >> CSHIFT;
      size_t base = (size_t)(bm + r) * HEADS;
      if (h0 == h1) O[base + h0] = va + vb;           // layer1: head = 128 cols
      else { O[base + h0] = va; O[base + h1] = vb; }  // layer2: head = 64 cols
    }
  }
}

// ---- CSR aggregation: barrier-free, LDS-free, DEPTH-2 pipelined uint2 gathers ----
// NSPLIT blocks per node; block handles CPB = F/NSPLIT channels with BT = CPB/4
// threads (4 consecutive channels each). Batch k+1's 16 loads are issued BEFORE
// consuming batch k (~32 loads in flight/wave; wave count unchanged - R14).
// NOTE R7 lesson: NO global-atomic pool fusion (5M device atomics = 265 µs,
// atomic-throughput bound; G12 violated). Output is plain stores; pool_k does
// the graph reduction with ~B atomics per channel-strip.
template <int F, int CSHIFT, int BT, int NSPLIT, typename OT>
__global__ __launch_bounds__(BT) void aggregate_k(const ushort_t* __restrict__ hb,
                                                  const float* __restrict__ asrc,
                                                  const float* __restrict__ adst,
                                                  const int* __restrict__ offs,
                                                  const int* __restrict__ psrc,
                                                  const float* __restrict__ bias,
                                                  OT* __restrict__ out) {
  constexpr int CPB = F / NSPLIT;
  static_assert(CPB == 4 * BT, "CPB/thread mismatch");
  int nb = blockIdx.x;
  int n = nb / NSPLIT;
  int coff = (nb - n * NSPLIT) * CPB;
  int t = threadIdx.x;
  int c0 = coff + 4 * t;
  int hh = c0 >> CSHIFT;
  float adn = adst[n * HEADS + hh];
  int e0 = offs[n], e1 = offs[n + 1];
  float4 acc = make_float4(0.f, 0.f, 0.f, 0.f);
  float wsum = 0.f;

  int i = e0;
  uint2 rA[8];
  float avA[8];
  bool haveA = (i + 8 <= e1);
  if (haveA) {
    int sA[8];
#pragma unroll
    for (int u = 0; u < 8; u++) sA[u] = psrc[i + u];
#pragma unroll
    for (int u = 0; u < 8; u++) rA[u] = *(const uint2*)&hb[(size_t)sA[u] * F + c0];
#pragma unroll
    for (int u = 0; u < 8; u++) avA[u] = asrc[sA[u] * HEADS + hh];
  }
  while (i + 16 <= e1) {
    // issue batch B (16 loads) before consuming batch A
    int sB[8];
    uint2 rB[8];
    float avB[8];
#pragma unroll
    for (int u = 0; u < 8; u++) sB[u] = psrc[i + 8 + u];
#pragma unroll
    for (int u = 0; u < 8; u++) rB[u] = *(const uint2*)&hb[(size_t)sB[u] * F + c0];
#pragma unroll
    for (int u = 0; u < 8; u++) avB[u] = asrc[sB[u] * HEADS + hh];
#pragma unroll
    for (int u = 0; u < 8; u++) {
      float v = avA[u] + adn;
      v = (v > 0.f) ? v : NEG * v;  // leaky_relu(0.2)
      float w = __expf(v);          // hw v_exp_f32; shift-invariant softmax
      float4 f = bf4(rA[u]);
      wsum += w;
      acc.x += w * f.x;
      acc.y += w * f.y;
      acc.z += w * f.z;
      acc.w += w * f.w;
    }
    i += 8;
#pragma unroll
    for (int u = 0; u < 8; u++) { rA[u] = rB[u]; avA[u] = avB[u]; }
  }
  if (haveA) {
#pragma unroll
    for (int u = 0; u < 8; u++) {
      float v = avA[u] + adn;
      v = (v > 0.f) ? v : NEG * v;
      float w = __expf(v);
      float4 f = bf4(rA[u]);
      wsum += w;
      acc.x += w * f.x;
      acc.y += w * f.y;
      acc.z += w * f.z;
      acc.w += w * f.w;
    }
    i += 8;
  }
  for (; i < e1; i++) {
    int ss = psrc[i];
    float v = asrc[ss * HEADS + hh] + adn;
    v = (v > 0.f) ? v : NEG * v;
    float w = __expf(v);
    float4 f = bf4(*(const uint2*)&hb[(size_t)ss * F + c0]);
    wsum += w;
    acc.x += w * f.x; acc.y += w * f.y;
    acc.z += w * f.z; acc.w += w * f.w;
  }

  float inv = 1.f / wsum;
  float v0 = elu_f(acc.x * inv + bias[c0]);
  float v1 = elu_f(acc.y * inv + bias[c0 + 1]);
  float v2 = elu_f(acc.z * inv + bias[c0 + 2]);
  float v3 = elu_f(acc.w * inv + bias[c0 + 3]);
  if constexpr (sizeof(OT) == 2) {
    unsigned p0 = (unsigned)f2bf(v0) | ((unsigned)f2bf(v1) << 16);
    unsigned p1 = (unsigned)f2bf(v2) | ((unsigned)f2bf(v3) << 16);
    *(uint2*)&((ushort_t*)out)[(size_t)n * F + c0] = make_uint2(p0, p1);
  } else {
    *(float4*)&((float*)out)[(size_t)n * F + c0] = make_float4(v0, v1, v2, v3);
  }
}

__global__ __launch_bounds__(256) void pool_k(const float* __restrict__ g,
                                              const int* __restrict__ batch,
                                              float* __restrict__ sums, int Nn) {
  int c = blockIdx.x * 256 + threadIdx.x;  // 0..511
  int n0 = blockIdx.y * 50;
  int n1 = min(n0 + 50, Nn);
  if (n0 >= n1) return;
  float acc = 0.f;
  int cur = batch[n0];
  for (int n = n0; n < n1; n++) {
    int b = batch[n];
    if (b != cur) { atomicAdd(&sums[cur * 512 + c], acc); acc = 0.f; cur = b; }
    acc += g[(size_t)n * 512 + c];
  }
  atomicAdd(&sums[cur * 512 + c], acc);
}

// ---------------- mean + fc1(elu) + fc2, one block ----------------
__global__ __launch_bounds__(512) void mlp_k(const float* __restrict__ sums,
                                             const int* __restrict__ bstart,
                                             const int* __restrict__ bend,
                                             const float* __restrict__ w1,
                                             const float* __restrict__ b1,
                                             const float* __restrict__ w2,
                                             const float* __restrict__ b2,
                                             float* __restrict__ out) {
  __shared__ float gm[16 * 512];
  __shared__ float t1[16 * 32];
  int t = threadIdx.x;
  for (int i = t; i < 16 * 512; i += 512) {
    int b = i >> 9;
    float c = (float)(bend[b] - bstart[b]);
    gm[i] = sums[i] / fmaxf(c, 1.f);
  }
  __syncthreads();
  {
    int b = t >> 5, j = t & 31;
    float s = b1[j];
    for (int k = 0; k < 512; k++) s += gm[(b << 9) + k] * w1[k * 32 + j];
    t1[t] = elu_f(s);
  }
  __syncthreads();
  if (t < 160) {
    int b = t / 10, j = t - b * 10;
    float s = b2[j];
#pragma unroll
    for (int k = 0; k < 32; k++) s += t1[b * 32 + k] * w2[k * 10 + j];
    out[t] = s;
  }
}

extern "C" void kernel_launch(void* const* d_in, const int* in_sizes, int n_in,
                              void* d_out, int out_size, void* d_ws, size_t ws_size,
                              hipStream_t stream) {
  const float* x   = (const float*)d_in[0];
  const int*   ei  = (const int*)d_in[1];
  const int* batch = (const int*)d_in[2];
  const float* W1  = (const float*)d_in[3];
  const float* as1 = (const float*)d_in[4];
  const float* ad1 = (const float*)d_in[5];
  const float* b1  = (const float*)d_in[6];
  const float* W2  = (const float*)d_in[7];
  const float* as2 = (const float*)d_in[8];
  const float* ad2 = (const float*)d_in[9];
  const float* b2  = (const float*)d_in[10];
  const float* f1w = (const float*)d_in[11];
  const float* f1b = (const float*)d_in[12];
  const float* f2w = (const float*)d_in[13];
  const float* f2b = (const float*)d_in[14];
  float* out = (float*)d_out;

  const int Nn = in_sizes[2];      // 10000
  const int E = in_sizes[1] / 2;   // 160000
  const int Etot = E + Nn;         // self loops appended

  // ---- workspace layout (4B words, 64-word aligned) ----
  size_t off = 0;
  auto alloc = [&](size_t elems) { size_t o = off; off += (elems + 63) & ~(size_t)63; return o; };
  int* wsi = (int*)d_ws;
  float* wsf = (float*)d_ws;

  size_t o_deg  = alloc(Nn);
  size_t o_pool = alloc(16 * 512);
  size_t zero_words = off;               // only deg+pool accumulate -> zero each call
  size_t o_as1  = alloc((size_t)Nn * 8); // plain-stored by GEMM epilogue
  size_t o_ad1  = alloc((size_t)Nn * 8);
  size_t o_as2  = alloc((size_t)Nn * 8);
  size_t o_ad2  = alloc((size_t)Nn * 8);
  size_t o_bst  = alloc(64);
  size_t o_ben  = alloc(64);
  size_t o_offs = alloc(Nn + 1);
  size_t o_cur  = alloc(Nn);
  size_t o_src  = alloc(Etot);
  size_t o_dst  = alloc(Etot);
  size_t o_psrc = alloc(Etot);
  size_t o_xb   = alloc((size_t)Nn * 128 / 2);   // x bf16  [N,128]
  size_t o_w1t  = alloc(1024 * 128 / 2);         // W1^T bf16 [1024,128]
  size_t o_w2t  = alloc(512 * 1024 / 2);         // W2^T bf16 [512,1024]
  size_t o_h    = alloc((size_t)Nn * 1024 / 2);  // h bf16 [N,1024] (layer2 uses first half)
  size_t o_g    = alloc((size_t)Nn * 1024);      // g1 bf16 (first half) then g2 fp32

  ushort_t* xb  = (ushort_t*)(wsi + o_xb);
  ushort_t* w1t = (ushort_t*)(wsi + o_w1t);
  ushort_t* w2t = (ushort_t*)(wsi + o_w2t);
  ushort_t* hb  = (ushort_t*)(wsi + o_h);
  ushort_t* g1b = (ushort_t*)(wsi + o_g);

  int eb = (Etot + 255) / 256;

  int nx4 = Nn * 128 / 4;
  int ep_work = (int)((zero_words > (size_t)nx4 ? zero_words : (size_t)nx4));
  int init_blocks = 640 + (ep_work + 255) / 256;
  init_k<<<init_blocks, 256, 0, stream>>>(wsi, (int)zero_words, x, xb,
                                          W1, w1t, W2, w2t, nx4);
  prep_k<<<eb, 256, 0, stream>>>(ei, wsi + o_src, wsi + o_dst, wsi + o_deg,
                                 batch, wsi + o_bst, wsi + o_ben, E, Nn);
  scan_k<<<1, 1024, 0, stream>>>(wsi + o_deg, wsi + o_offs, wsi + o_cur, Nn);
  scatter_k<<<eb, 256, 0, stream>>>(wsi + o_src, wsi + o_dst, wsi + o_cur,
                                    wsi + o_psrc, Etot);

  // ---- layer 1: 128 -> 8x128 ----
  mfma_gemm_k<<<dim3(1024 / 128, (Nn + 127) / 128), 256, 0, stream>>>(
      xb, w1t, hb, as1, ad1, wsf + o_as1, wsf + o_ad1, Nn, 1024, 128, 7);
  aggregate_k<1024, 7, 128, 2, ushort_t><<<Nn * 2, 128, 0, stream>>>(
      hb, wsf + o_as1, wsf + o_ad1, wsi + o_offs, wsi + o_psrc, b1, g1b);

  // ---- layer 2: 1024 -> 8x64 ----
  mfma_gemm_k<<<dim3(512 / 128, (Nn + 127) / 128), 256, 0, stream>>>(
      g1b, w2t, hb, as2, ad2, wsf + o_as2, wsf + o_ad2, Nn, 512, 1024, 6);
  aggregate_k<512, 6, 64, 2, float><<<Nn * 2, 64, 0, stream>>>(
      hb, wsf + o_as2, wsf + o_ad2, wsi + o_offs, wsi + o_psrc, b2, wsf + o_g);

  // ---- pool + MLP ----
  pool_k<<<dim3(2, (Nn + 49) / 50), 256, 0, stream>>>(wsf + o_g, batch, wsf + o_pool, Nn);
  mlp_k<<<1, 512, 0, stream>>>(wsf + o_pool, wsi + o_bst, wsi + o_ben, f1w, f1b, f2w, f2b, out);
}

// Round 9
// 254.880 us; speedup vs baseline: 1.8451x; 1.0057x over previous
//
#include <hip/hip_runtime.h>
#include <math.h>

#define HEADS 8
#define NEG 0.2f

typedef unsigned short ushort_t;
typedef __attribute__((ext_vector_type(8))) short short8;
typedef float f32x4 __attribute__((ext_vector_type(4)));

__device__ inline ushort_t f2bf(float f) {
  union { float f; unsigned u; } v; v.f = f;
  unsigned r = (v.u + 0x7FFF + ((v.u >> 16) & 1)) >> 16;  // RNE
  return (ushort_t)r;
}

__device__ inline float4 bf4(uint2 v) {
  union { unsigned u; float f; } a, b, c, d;
  a.u = v.x << 16; b.u = v.x & 0xffff0000u;
  c.u = v.y << 16; d.u = v.y & 0xffff0000u;
  return make_float4(a.f, b.f, c.f, d.f);
}

// fast ELU: exp(v)-1 via hw v_exp_f32; |abs err| ~1e-7, fine vs 1.7e-3 threshold
__device__ inline float elu_f(float v) {
  return (v > 0.f) ? v : (__expf(v) - 1.f);
}

// async global->LDS, 16B per lane; LDS dest is wave-uniform base + lane*16
#define GLDS16(gp, lp)                                                          \
  __builtin_amdgcn_global_load_lds(                                             \
      (const __attribute__((address_space(1))) void*)(gp),                      \
      (__attribute__((address_space(3))) void*)(lp), 16, 0, 0)

// ---- fused init: LDS-tiled W transpose (coalesced both ways) + zero + x->bf16 ----
// blocks 0..639: 32x32 transpose tiles (W1: 128 tiles, W2: 512 tiles)
// blocks 640.. : zero accum region + cast x to bf16
__global__ __launch_bounds__(256) void init_k(int* __restrict__ ws, int zero_words,
                                              const float* __restrict__ x,
                                              ushort_t* __restrict__ xb,
                                              const float* __restrict__ W1,
                                              ushort_t* __restrict__ w1t,
                                              const float* __restrict__ W2,
                                              ushort_t* __restrict__ w2t, int nx4) {
  __shared__ float tile[32][33];
  int blk = blockIdx.x;
  if (blk < 640) {
    const float* W; ushort_t* Wt; int K, N, tk, tn;
    if (blk < 128) { W = W1; Wt = w1t; K = 128; N = 1024; tk = blk >> 5; tn = blk & 31; }
    else { W = W2; Wt = w2t; K = 1024; N = 512; int t = blk - 128; tk = t >> 4; tn = t & 15; }
    int tx = threadIdx.x & 31, ty = threadIdx.x >> 5;  // 32 x 8
    int k0 = tk * 32, n0 = tn * 32;
#pragma unroll
    for (int r = 0; r < 4; r++)
      tile[ty + r * 8][tx] = W[(size_t)(k0 + ty + r * 8) * N + n0 + tx];  // coalesced read
    __syncthreads();
#pragma unroll
    for (int r = 0; r < 4; r++)
      Wt[(size_t)(n0 + ty + r * 8) * K + k0 + tx] = f2bf(tile[tx][ty + r * 8]);  // coalesced write
  } else {
    int i = (blk - 640) * 256 + threadIdx.x;
    if (i < zero_words) ws[i] = 0;
    if (i < nx4) {
      float4 v = ((const float4*)x)[i];
      ushort_t o[4] = {f2bf(v.x), f2bf(v.y), f2bf(v.z), f2bf(v.w)};
      *(uint2*)&xb[i * 4] = *(uint2*)o;
    }
  }
}

// -- edge prep + degree count + batch bounds fused (batch sorted; no atomics) --
__global__ void prep_k(const int* __restrict__ ei, int* __restrict__ src,
                       int* __restrict__ dst, int* __restrict__ deg,
                       const int* __restrict__ batch, int* __restrict__ bstart,
                       int* __restrict__ bend, int E, int Nn) {
  int i = blockIdx.x * blockDim.x + threadIdx.x;
  if (i < Nn) {
    int b = batch[i];
    if (i == 0 || batch[i - 1] != b) bstart[b] = i;
    if (i == Nn - 1 || batch[i + 1] != b) bend[b] = i + 1;
  }
  if (i >= E + Nn) return;
  int s, d;
  if (i < E) { s = ei[i]; d = ei[E + i]; }
  else       { s = d = i - E; }
  src[i] = s;
  dst[i] = d;
  atomicAdd(&deg[d], 1);
}

// single-block scan over N, 4 elems/thread (4096/chunk), wave-shuffle based
__global__ __launch_bounds__(1024) void scan_k(const int* __restrict__ deg,
                                               int* __restrict__ offs,
                                               int* __restrict__ cursor, int Nn) {
  __shared__ int wtot[16];
  __shared__ int wexcl[16];
  __shared__ int soff_s;
  int t = threadIdx.x;
  int lane = t & 63, w = t >> 6;
  if (t == 0) soff_s = 0;
  __syncthreads();
  for (int base = 0; base < Nn; base += 4096) {
    int idx = base + 4 * t;
    int4 v = make_int4(0, 0, 0, 0);
    if (idx + 3 < Nn) v = *(const int4*)&deg[idx];
    else {
      if (idx < Nn)     v.x = deg[idx];
      if (idx + 1 < Nn) v.y = deg[idx + 1];
      if (idx + 2 < Nn) v.z = deg[idx + 2];
      if (idx + 3 < Nn) v.w = deg[idx + 3];
    }
    int s1 = v.x, s2 = s1 + v.y, s3 = s2 + v.z, s4 = s3 + v.w;
    int sc = s4;  // wave-inclusive scan of per-thread totals
#pragma unroll
    for (int o = 1; o < 64; o <<= 1) {
      int x = __shfl_up(sc, o);
      if (lane >= o) sc += x;
    }
    if (lane == 63) wtot[w] = sc;
    __syncthreads();
    if (w == 0) {
      int tv = (lane < 16) ? wtot[lane] : 0;
      int ts = tv;
#pragma unroll
      for (int o = 1; o < 16; o <<= 1) {
        int x = __shfl_up(ts, o);
        if (lane >= o) ts += x;
      }
      if (lane < 16) wexcl[lane] = ts - tv;
      if (lane == 15) wtot[15] = ts;  // chunk total
    }
    __syncthreads();
    int excl = soff_s + wexcl[w] + (sc - s4);
    int o0 = excl, o1 = excl + s1, o2 = excl + s2, o3 = excl + s3;
    if (idx < Nn)     { offs[idx] = o0;     cursor[idx] = o0; }
    if (idx + 1 < Nn) { offs[idx + 1] = o1; cursor[idx + 1] = o1; }
    if (idx + 2 < Nn) { offs[idx + 2] = o2; cursor[idx + 2] = o2; }
    if (idx + 3 < Nn) { offs[idx + 3] = o3; cursor[idx + 3] = o3; }
    int chunk_total = wtot[15];
    __syncthreads();
    if (t == 0) soff_s += chunk_total;
    __syncthreads();
  }
  if (t == 0) offs[Nn] = soff_s;
}

// scatter src values directly into CSR slot order (no perm indirection)
__global__ void scatter_k(const int* __restrict__ src, const int* __restrict__ dst,
                          int* __restrict__ cursor, int* __restrict__ psrc, int Etot) {
  int i = blockIdx.x * blockDim.x + threadIdx.x;
  if (i >= Etot) return;
  int p = atomicAdd(&cursor[dst[i]], 1);
  psrc[p] = src[i];
}

// ------- bf16 MFMA GEMM + fused alpha epilogue: Cb[M,N](bf16) = A @ Bt^T -------
// 128x128 tile, 256 threads (4 waves 2x2), BK=64, dbuf 2-phase GLDS pipeline.
// Epilogue (R6-verified): C tile staged through LDS -> full-line uint4 stores;
// NO device atomics (block-exclusive (row,head) ownership, LDS cross-wave
// reduce + plain stores).
__global__ __launch_bounds__(256) void mfma_gemm_k(const ushort_t* __restrict__ A,
                                                   const ushort_t* __restrict__ Bt,
                                                   ushort_t* __restrict__ Cb,
                                                   const float* __restrict__ att_s,
                                                   const float* __restrict__ att_d,
                                                   float* __restrict__ asrc,
                                                   float* __restrict__ adst,
                                                   int M, int N, int K, int CSHIFT) {
  __shared__ __attribute__((aligned(16))) ushort_t lds[32768];  // 64KB, multi-use
  // K-loop: As buf b = lds[b*8192], Bs buf b = lds[16384 + b*8192]
  // epilogue: C tile [128][136] at lds[0]; alpha partials at lds[17472]
  int tid = threadIdx.x;
  int lane = tid & 63;
  int wave = tid >> 6;
  int wm = (wave >> 1) * 64, wn = (wave & 1) * 64;
  int bm = blockIdx.y * 128, bn = blockIdx.x * 128;
  int lrow = lane & 15, lq = lane >> 4;

  f32x4 acc[4][4];
#pragma unroll
  for (int i = 0; i < 4; i++)
#pragma unroll
    for (int j = 0; j < 4; j++) acc[i][j] = 0.f;

  int srow = lane >> 3;                    // row within chunk (== row&7)
  int scol = 8 * ((lane & 7) ^ srow);      // pre-swizzled column (elems)
  const ushort_t* pa[4];
  const ushort_t* pb[4];
  int lofs[4];
#pragma unroll
  for (int c = 0; c < 4; c++) {
    int row = wave * 32 + c * 8 + srow;
    int ga = min(bm + row, M - 1);         // clamp tail rows (dup of last row)
    pa[c] = &A[(size_t)ga * K + scol];
    pb[c] = &Bt[(size_t)(bn + row) * K + scol];
    lofs[c] = (wave * 4 + c) * 512;        // 1KiB chunks, wave-uniform base
  }

  auto stage = [&](int buf, int k0) {
#pragma unroll
    for (int c = 0; c < 4; c++) GLDS16(pa[c] + k0, &lds[buf * 8192 + lofs[c]]);
#pragma unroll
    for (int c = 0; c < 4; c++) GLDS16(pb[c] + k0, &lds[16384 + buf * 8192 + lofs[c]]);
  };

  auto compute = [&](int buf) {
    const ushort_t* Asb = &lds[buf * 8192];
    const ushort_t* Bsb = &lds[16384 + buf * 8192];
#pragma unroll
    for (int ks = 0; ks < 2; ks++) {
      short8 af[4], bfr[4];
#pragma unroll
      for (int t = 0; t < 4; t++) {
        int cbs = (ks * 64 + lq * 16) ^ ((lrow & 7) << 4);  // swizzled byte col
        af[t]  = *(const short8*)&Asb[(wm + t * 16 + lrow) * 64 + (cbs >> 1)];
        bfr[t] = *(const short8*)&Bsb[(wn + t * 16 + lrow) * 64 + (cbs >> 1)];
      }
#pragma unroll
      for (int i = 0; i < 4; i++)
#pragma unroll
        for (int j = 0; j < 4; j++)
          acc[i][j] = __builtin_amdgcn_mfma_f32_16x16x32_bf16(af[i], bfr[j], acc[i][j], 0, 0, 0);
    }
  };

  int NT = K >> 6;
  stage(0, 0);
  asm volatile("s_waitcnt vmcnt(0)" ::: "memory");
  __builtin_amdgcn_s_barrier();
  int cur = 0;
  for (int t = 0; t + 1 < NT; ++t) {
    stage(cur ^ 1, (t + 1) << 6);   // prefetch next K-tile; lands during compute
    compute(cur);
    asm volatile("s_waitcnt vmcnt(0)" ::: "memory");  // prefetch done (own loads)
    __builtin_amdgcn_s_barrier();   // publishes next buf + protects cur from overwrite
    cur ^= 1;
  }
  compute(cur);  // last tile, no prefetch

  __syncthreads();  // all waves done reading staging LDS -> safe to alias

  ushort_t* Cl = lds;                       // [128][136] bf16 (pad 136: 16B-aligned rows)
  float* pls = (float*)&lds[17472];         // [4 waves][64 rows] alpha-src partials
  float* pld = pls + 256;                   // [4][64] alpha-dst partials

  // ---- alpha partials (fp32, pre-rounding): 16-lane shfl reduce -> LDS ----
  {
    float avs[4], avd[4];
#pragma unroll
    for (int j = 0; j < 4; j++) {
      int col = bn + wn + j * 16 + lrow;  // att [H][N/H] flat == column index
      avs[j] = att_s[col];
      avd[j] = att_d[col];
    }
#pragma unroll
    for (int i = 0; i < 4; i++) {
#pragma unroll
      for (int r = 0; r < 4; r++) {
        float ps = 0.f, pd = 0.f;
#pragma unroll
        for (int j = 0; j < 4; j++) {
          float v = acc[i][j][r];
          ps += v * avs[j];
          pd += v * avd[j];
        }
#pragma unroll
        for (int o = 1; o < 16; o <<= 1) {
          ps += __shfl_xor(ps, o);
          pd += __shfl_xor(pd, o);
        }
        if (lrow == 0) {
          int rr = i * 16 + lq * 4 + r;   // 0..63 within wave tile
          pls[wave * 64 + rr] = ps;
          pld[wave * 64 + rr] = pd;
        }
      }
    }
  }

  // ---- C tile -> LDS (bf16) ----
#pragma unroll
  for (int i = 0; i < 4; i++) {
#pragma unroll
    for (int j = 0; j < 4; j++) {
      int col = wn + j * 16 + lrow;
#pragma unroll
      for (int r = 0; r < 4; r++) {
        int row = wm + i * 16 + lq * 4 + r;  // C/D: col=lane&15, row=(lane>>4)*4+reg
        Cl[row * 136 + col] = f2bf(acc[i][j][r]);
      }
    }
  }
  __syncthreads();

  // ---- coalesced C store: full 64B-line writes (16 rows x 16 uint4 per pass) ----
#pragma unroll
  for (int p = 0; p < 8; p++) {
    int row = p * 16 + (tid >> 4);
    int col8 = (tid & 15) * 8;
    if (bm + row < M)
      *(uint4*)&Cb[(size_t)(bm + row) * N + bn + col8] = *(const uint4*)&Cl[row * 136 + col8];
  }

  // ---- alpha store: plain stores, block-exclusive (row,head) ownership ----
  {
    int r = tid & 127, half = tid >> 7;     // 256 threads: 128 rows x {src,dst}
    if (bm + r < M) {
      const float* P = half ? pld : pls;
      float* O = half ? adst : asrc;
      int w0 = (r >> 6) * 2, idx = r & 63;
      float va = P[w0 * 64 + idx];          // wn=0 wave half (cols bn..bn+63)
      float vb = P[(w0 + 1) * 64 + idx];    // wn=64 wave half (cols bn+64..bn+127)
      int h0 = bn >> CSHIFT, h1 = (bn + 64) >> CSHIFT;
      size_t base = (size_t)(bm + r) * HEADS;
      if (h0 == h1) O[base + h0] = va + vb;           // layer1: head = 128 cols
      else { O[base + h0] = va; O[base + h1] = vb; }  // layer2: head = 64 cols
    }
  }
}

// ---- CSR aggregation: barrier-free, LDS-free, depth-2 pipelined uint2 gathers ----
// NSPLIT blocks per node; block handles CPB = F/NSPLIT channels with BT = CPB/4
// threads (4 consecutive channels each).
// WAVE-LEVEL ALPHA SHARING (R8 PMC: VALUBusy 61% with 32x-redundant per-edge
// exp/lrelu/asrc-gather): within each wave, only lane gb+u (u<8) of each G-lane
// head group computes edge u's softmax weight; consumers fetch via one __shfl
// per edge. Bit-identical math (same fp32 chain, same head). Scattered asrc
// loads and v_exp drop ~8x; ~3 VALU/edge/thread removed. Next batch's alpha is
// computed in the prefetch phase (hides under consume). Tail loop unchanged.
// NOTE R7 lesson: NO global-atomic pool fusion (5M device atomics = 265 µs).
template <int F, int CSHIFT, int BT, int NSPLIT, typename OT>
__global__ __launch_bounds__(BT) void aggregate_k(const ushort_t* __restrict__ hb,
                                                  const float* __restrict__ asrc,
                                                  const float* __restrict__ adst,
                                                  const int* __restrict__ offs,
                                                  const int* __restrict__ psrc,
                                                  const float* __restrict__ bias,
                                                  OT* __restrict__ out) {
  constexpr int CPB = F / NSPLIT;
  constexpr int G = (1 << CSHIFT) >> 2;  // threads per head within a wave
  static_assert(CPB == 4 * BT, "CPB/thread mismatch");
  static_assert(G >= 8 && G <= 64, "head group must cover the 8-edge batch");
  int nb = blockIdx.x;
  int n = nb / NSPLIT;
  int coff = (nb - n * NSPLIT) * CPB;
  int t = threadIdx.x;
  int c0 = coff + 4 * t;
  int hh = c0 >> CSHIFT;
  int lane = t & 63;
  int sub = lane & (G - 1);       // index within head group
  int gb = lane & ~(G - 1);       // head group base lane (shfl source base)
  float adn = adst[n * HEADS + hh];
  int e0 = offs[n], e1 = offs[n + 1];
  float4 acc = make_float4(0.f, 0.f, 0.f, 0.f);
  float wsum = 0.f;

  int i = e0;
  uint2 rA[8];
  float myWA = 0.f;               // this lane's alpha for edge `sub` (sub<8 only)
  bool haveA = (i + 8 <= e1);
  if (haveA) {
    int sA[8];
#pragma unroll
    for (int u = 0; u < 8; u++) sA[u] = psrc[i + u];
#pragma unroll
    for (int u = 0; u < 8; u++) rA[u] = *(const uint2*)&hb[(size_t)sA[u] * F + c0];
    int ms = psrc[i + (sub < 8 ? sub : 0)];
    float v = asrc[ms * HEADS + hh] + adn;
    v = (v > 0.f) ? v : NEG * v;
    myWA = __expf(v);
  }
  while (i + 16 <= e1) {
    // issue batch B's gathers + compute batch B's alpha before consuming A
    int sB[8];
    uint2 rB[8];
#pragma unroll
    for (int u = 0; u < 8; u++) sB[u] = psrc[i + 8 + u];
#pragma unroll
    for (int u = 0; u < 8; u++) rB[u] = *(const uint2*)&hb[(size_t)sB[u] * F + c0];
    int ms = psrc[i + 8 + (sub < 8 ? sub : 0)];
    float vb = asrc[ms * HEADS + hh] + adn;
    vb = (vb > 0.f) ? vb : NEG * vb;
    float myWB = __expf(vb);
#pragma unroll
    for (int u = 0; u < 8; u++) {
      float w = __shfl(myWA, gb + u);
      float4 f = bf4(rA[u]);
      wsum += w;
      acc.x += w * f.x;
      acc.y += w * f.y;
      acc.z += w * f.z;
      acc.w += w * f.w;
    }
    i += 8;
#pragma unroll
    for (int u = 0; u < 8; u++) rA[u] = rB[u];
    myWA = myWB;
  }
  if (haveA) {
#pragma unroll
    for (int u = 0; u < 8; u++) {
      float w = __shfl(myWA, gb + u);
      float4 f = bf4(rA[u]);
      wsum += w;
      acc.x += w * f.x;
      acc.y += w * f.y;
      acc.z += w * f.z;
      acc.w += w * f.w;
    }
    i += 8;
  }
  for (; i < e1; i++) {
    int ss = psrc[i];
    float v = asrc[ss * HEADS + hh] + adn;
    v = (v > 0.f) ? v : NEG * v;
    float w = __expf(v);
    float4 f = bf4(*(const uint2*)&hb[(size_t)ss * F + c0]);
    wsum += w;
    acc.x += w * f.x; acc.y += w * f.y;
    acc.z += w * f.z; acc.w += w * f.w;
  }

  float inv = 1.f / wsum;
  float v0 = elu_f(acc.x * inv + bias[c0]);
  float v1 = elu_f(acc.y * inv + bias[c0 + 1]);
  float v2 = elu_f(acc.z * inv + bias[c0 + 2]);
  float v3 = elu_f(acc.w * inv + bias[c0 + 3]);
  if constexpr (sizeof(OT) == 2) {
    unsigned p0 = (unsigned)f2bf(v0) | ((unsigned)f2bf(v1) << 16);
    unsigned p1 = (unsigned)f2bf(v2) | ((unsigned)f2bf(v3) << 16);
    *(uint2*)&((ushort_t*)out)[(size_t)n * F + c0] = make_uint2(p0, p1);
  } else {
    *(float4*)&((float*)out)[(size_t)n * F + c0] = make_float4(v0, v1, v2, v3);
  }
}

__global__ __launch_bounds__(256) void pool_k(const float* __restrict__ g,
                                              const int* __restrict__ batch,
                                              float* __restrict__ sums, int Nn) {
  int c = blockIdx.x * 256 + threadIdx.x;  // 0..511
  int n0 = blockIdx.y * 50;
  int n1 = min(n0 + 50, Nn);
  if (n0 >= n1) return;
  float acc = 0.f;
  int cur = batch[n0];
  for (int n = n0; n < n1; n++) {
    int b = batch[n];
    if (b != cur) { atomicAdd(&sums[cur * 512 + c], acc); acc = 0.f; cur = b; }
    acc += g[(size_t)n * 512 + c];
  }
  atomicAdd(&sums[cur * 512 + c], acc);
}

// ---------------- mean + fc1(elu) + fc2, one block ----------------
__global__ __launch_bounds__(512) void mlp_k(const float* __restrict__ sums,
                                             const int* __restrict__ bstart,
                                             const int* __restrict__ bend,
                                             const float* __restrict__ w1,
                                             const float* __restrict__ b1,
                                             const float* __restrict__ w2,
                                             const float* __restrict__ b2,
                                             float* __restrict__ out) {
  __shared__ float gm[16 * 512];
  __shared__ float t1[16 * 32];
  int t = threadIdx.x;
  for (int i = t; i < 16 * 512; i += 512) {
    int b = i >> 9;
    float c = (float)(bend[b] - bstart[b]);
    gm[i] = sums[i] / fmaxf(c, 1.f);
  }
  __syncthreads();
  {
    int b = t >> 5, j = t & 31;
    float s = b1[j];
    for (int k = 0; k < 512; k++) s += gm[(b << 9) + k] * w1[k * 32 + j];
    t1[t] = elu_f(s);
  }
  __syncthreads();
  if (t < 160) {
    int b = t / 10, j = t - b * 10;
    float s = b2[j];
#pragma unroll
    for (int k = 0; k < 32; k++) s += t1[b * 32 + k] * w2[k * 10 + j];
    out[t] = s;
  }
}

extern "C" void kernel_launch(void* const* d_in, const int* in_sizes, int n_in,
                              void* d_out, int out_size, void* d_ws, size_t ws_size,
                              hipStream_t stream) {
  const float* x   = (const float*)d_in[0];
  const int*   ei  = (const int*)d_in[1];
  const int* batch = (const int*)d_in[2];
  const float* W1  = (const float*)d_in[3];
  const float* as1 = (const float*)d_in[4];
  const float* ad1 = (const float*)d_in[5];
  const float* b1  = (const float*)d_in[6];
  const float* W2  = (const float*)d_in[7];
  const float* as2 = (const float*)d_in[8];
  const float* ad2 = (const float*)d_in[9];
  const float* b2  = (const float*)d_in[10];
  const float* f1w = (const float*)d_in[11];
  const float* f1b = (const float*)d_in[12];
  const float* f2w = (const float*)d_in[13];
  const float* f2b = (const float*)d_in[14];
  float* out = (float*)d_out;

  const int Nn = in_sizes[2];      // 10000
  const int E = in_sizes[1] / 2;   // 160000
  const int Etot = E + Nn;         // self loops appended

  // ---- workspace layout (4B words, 64-word aligned) ----
  size_t off = 0;
  auto alloc = [&](size_t elems) { size_t o = off; off += (elems + 63) & ~(size_t)63; return o; };
  int* wsi = (int*)d_ws;
  float* wsf = (float*)d_ws;

  size_t o_deg  = alloc(Nn);
  size_t o_pool = alloc(16 * 512);
  size_t zero_words = off;               // only deg+pool accumulate -> zero each call
  size_t o_as1  = alloc((size_t)Nn * 8); // plain-stored by GEMM epilogue
  size_t o_ad1  = alloc((size_t)Nn * 8);
  size_t o_as2  = alloc((size_t)Nn * 8);
  size_t o_ad2  = alloc((size_t)Nn * 8);
  size_t o_bst  = alloc(64);
  size_t o_ben  = alloc(64);
  size_t o_offs = alloc(Nn + 1);
  size_t o_cur  = alloc(Nn);
  size_t o_src  = alloc(Etot);
  size_t o_dst  = alloc(Etot);
  size_t o_psrc = alloc(Etot);
  size_t o_xb   = alloc((size_t)Nn * 128 / 2);   // x bf16  [N,128]
  size_t o_w1t  = alloc(1024 * 128 / 2);         // W1^T bf16 [1024,128]
  size_t o_w2t  = alloc(512 * 1024 / 2);         // W2^T bf16 [512,1024]
  size_t o_h    = alloc((size_t)Nn * 1024 / 2);  // h bf16 [N,1024] (layer2 uses first half)
  size_t o_g    = alloc((size_t)Nn * 1024);      // g1 bf16 (first half) then g2 fp32

  ushort_t* xb  = (ushort_t*)(wsi + o_xb);
  ushort_t* w1t = (ushort_t*)(wsi + o_w1t);
  ushort_t* w2t = (ushort_t*)(wsi + o_w2t);
  ushort_t* hb  = (ushort_t*)(wsi + o_h);
  ushort_t* g1b = (ushort_t*)(wsi + o_g);

  int eb = (Etot + 255) / 256;

  int nx4 = Nn * 128 / 4;
  int ep_work = (int)((zero_words > (size_t)nx4 ? zero_words : (size_t)nx4));
  int init_blocks = 640 + (ep_work + 255) / 256;
  init_k<<<init_blocks, 256, 0, stream>>>(wsi, (int)zero_words, x, xb,
                                          W1, w1t, W2, w2t, nx4);
  prep_k<<<eb, 256, 0, stream>>>(ei, wsi + o_src, wsi + o_dst, wsi + o_deg,
                                 batch, wsi + o_bst, wsi + o_ben, E, Nn);
  scan_k<<<1, 1024, 0, stream>>>(wsi + o_deg, wsi + o_offs, wsi + o_cur, Nn);
  scatter_k<<<eb, 256, 0, stream>>>(wsi + o_src, wsi + o_dst, wsi + o_cur,
                                    wsi + o_psrc, Etot);

  // ---- layer 1: 128 -> 8x128 ----
  mfma_gemm_k<<<dim3(1024 / 128, (Nn + 127) / 128), 256, 0, stream>>>(
      xb, w1t, hb, as1, ad1, wsf + o_as1, wsf + o_ad1, Nn, 1024, 128, 7);
  aggregate_k<1024, 7, 128, 2, ushort_t><<<Nn * 2, 128, 0, stream>>>(
      hb, wsf + o_as1, wsf + o_ad1, wsi + o_offs, wsi + o_psrc, b1, g1b);

  // ---- layer 2: 1024 -> 8x64 ----
  mfma_gemm_k<<<dim3(512 / 128, (Nn + 127) / 128), 256, 0, stream>>>(
      g1b, w2t, hb, as2, ad2, wsf + o_as2, wsf + o_ad2, Nn, 512, 1024, 6);
  aggregate_k<512, 6, 64, 2, float><<<Nn * 2, 64, 0, stream>>>(
      hb, wsf + o_as2, wsf + o_ad2, wsi + o_offs, wsi + o_psrc, b2, wsf + o_g);

  // ---- pool + MLP ----
  pool_k<<<dim3(2, (Nn + 49) / 50), 256, 0, stream>>>(wsf + o_g, batch, wsf + o_pool, Nn);
  mlp_k<<<1, 512, 0, stream>>>(wsf + o_pool, wsi + o_bst, wsi + o_ben, f1w, f1b, f2w, f2b, out);
}

// Round 10
// 250.757 us; speedup vs baseline: 1.8754x; 1.0164x over previous
//
#include <hip/hip_runtime.h>
#include <math.h>

#define HEADS 8
#define NEG 0.2f

typedef unsigned short ushort_t;
typedef __attribute__((ext_vector_type(8))) short short8;
typedef float f32x4 __attribute__((ext_vector_type(4)));

__device__ inline ushort_t f2bf(float f) {
  union { float f; unsigned u; } v; v.f = f;
  unsigned r = (v.u + 0x7FFF + ((v.u >> 16) & 1)) >> 16;  // RNE
  return (ushort_t)r;
}

__device__ inline float4 bf4(uint2 v) {
  union { unsigned u; float f; } a, b, c, d;
  a.u = v.x << 16; b.u = v.x & 0xffff0000u;
  c.u = v.y << 16; d.u = v.y & 0xffff0000u;
  return make_float4(a.f, b.f, c.f, d.f);
}

// fast ELU: exp(v)-1 via hw v_exp_f32; |abs err| ~1e-7, fine vs 1.7e-3 threshold
__device__ inline float elu_f(float v) {
  return (v > 0.f) ? v : (__expf(v) - 1.f);
}

// async global->LDS, 16B per lane; LDS dest is wave-uniform base + lane*16
#define GLDS16(gp, lp)                                                          \
  __builtin_amdgcn_global_load_lds(                                             \
      (const __attribute__((address_space(1))) void*)(gp),                      \
      (__attribute__((address_space(3))) void*)(lp), 16, 0, 0)

// ---- fused init: LDS-tiled W transpose (coalesced both ways) + zero + x->bf16 ----
__global__ __launch_bounds__(256) void init_k(int* __restrict__ ws, int zero_words,
                                              const float* __restrict__ x,
                                              ushort_t* __restrict__ xb,
                                              const float* __restrict__ W1,
                                              ushort_t* __restrict__ w1t,
                                              const float* __restrict__ W2,
                                              ushort_t* __restrict__ w2t, int nx4) {
  __shared__ float tile[32][33];
  int blk = blockIdx.x;
  if (blk < 640) {
    const float* W; ushort_t* Wt; int K, N, tk, tn;
    if (blk < 128) { W = W1; Wt = w1t; K = 128; N = 1024; tk = blk >> 5; tn = blk & 31; }
    else { W = W2; Wt = w2t; K = 1024; N = 512; int t = blk - 128; tk = t >> 4; tn = t & 15; }
    int tx = threadIdx.x & 31, ty = threadIdx.x >> 5;  // 32 x 8
    int k0 = tk * 32, n0 = tn * 32;
#pragma unroll
    for (int r = 0; r < 4; r++)
      tile[ty + r * 8][tx] = W[(size_t)(k0 + ty + r * 8) * N + n0 + tx];  // coalesced read
    __syncthreads();
#pragma unroll
    for (int r = 0; r < 4; r++)
      Wt[(size_t)(n0 + ty + r * 8) * K + k0 + tx] = f2bf(tile[tx][ty + r * 8]);  // coalesced write
  } else {
    int i = (blk - 640) * 256 + threadIdx.x;
    if (i < zero_words) ws[i] = 0;
    if (i < nx4) {
      float4 v = ((const float4*)x)[i];
      ushort_t o[4] = {f2bf(v.x), f2bf(v.y), f2bf(v.z), f2bf(v.w)};
      *(uint2*)&xb[i * 4] = *(uint2*)o;
    }
  }
}

// -- edge prep + degree count + batch bounds fused (batch sorted; no atomics) --
__global__ void prep_k(const int* __restrict__ ei, int* __restrict__ src,
                       int* __restrict__ dst, int* __restrict__ deg,
                       const int* __restrict__ batch, int* __restrict__ bstart,
                       int* __restrict__ bend, int E, int Nn) {
  int i = blockIdx.x * blockDim.x + threadIdx.x;
  if (i < Nn) {
    int b = batch[i];
    if (i == 0 || batch[i - 1] != b) bstart[b] = i;
    if (i == Nn - 1 || batch[i + 1] != b) bend[b] = i + 1;
  }
  if (i >= E + Nn) return;
  int s, d;
  if (i < E) { s = ei[i]; d = ei[E + i]; }
  else       { s = d = i - E; }
  src[i] = s;
  dst[i] = d;
  atomicAdd(&deg[d], 1);
}

// single-block scan over N, 4 elems/thread (4096/chunk), wave-shuffle based
__global__ __launch_bounds__(1024) void scan_k(const int* __restrict__ deg,
                                               int* __restrict__ offs,
                                               int* __restrict__ cursor, int Nn) {
  __shared__ int wtot[16];
  __shared__ int wexcl[16];
  __shared__ int soff_s;
  int t = threadIdx.x;
  int lane = t & 63, w = t >> 6;
  if (t == 0) soff_s = 0;
  __syncthreads();
  for (int base = 0; base < Nn; base += 4096) {
    int idx = base + 4 * t;
    int4 v = make_int4(0, 0, 0, 0);
    if (idx + 3 < Nn) v = *(const int4*)&deg[idx];
    else {
      if (idx < Nn)     v.x = deg[idx];
      if (idx + 1 < Nn) v.y = deg[idx + 1];
      if (idx + 2 < Nn) v.z = deg[idx + 2];
      if (idx + 3 < Nn) v.w = deg[idx + 3];
    }
    int s1 = v.x, s2 = s1 + v.y, s3 = s2 + v.z, s4 = s3 + v.w;
    int sc = s4;  // wave-inclusive scan of per-thread totals
#pragma unroll
    for (int o = 1; o < 64; o <<= 1) {
      int x = __shfl_up(sc, o);
      if (lane >= o) sc += x;
    }
    if (lane == 63) wtot[w] = sc;
    __syncthreads();
    if (w == 0) {
      int tv = (lane < 16) ? wtot[lane] : 0;
      int ts = tv;
#pragma unroll
      for (int o = 1; o < 16; o <<= 1) {
        int x = __shfl_up(ts, o);
        if (lane >= o) ts += x;
      }
      if (lane < 16) wexcl[lane] = ts - tv;
      if (lane == 15) wtot[15] = ts;  // chunk total
    }
    __syncthreads();
    int excl = soff_s + wexcl[w] + (sc - s4);
    int o0 = excl, o1 = excl + s1, o2 = excl + s2, o3 = excl + s3;
    if (idx < Nn)     { offs[idx] = o0;     cursor[idx] = o0; }
    if (idx + 1 < Nn) { offs[idx + 1] = o1; cursor[idx + 1] = o1; }
    if (idx + 2 < Nn) { offs[idx + 2] = o2; cursor[idx + 2] = o2; }
    if (idx + 3 < Nn) { offs[idx + 3] = o3; cursor[idx + 3] = o3; }
    int chunk_total = wtot[15];
    __syncthreads();
    if (t == 0) soff_s += chunk_total;
    __syncthreads();
  }
  if (t == 0) offs[Nn] = soff_s;
}

// scatter src values directly into CSR slot order (no perm indirection)
__global__ void scatter_k(const int* __restrict__ src, const int* __restrict__ dst,
                          int* __restrict__ cursor, int* __restrict__ psrc, int Etot) {
  int i = blockIdx.x * blockDim.x + threadIdx.x;
  if (i >= Etot) return;
  int p = atomicAdd(&cursor[dst[i]], 1);
  psrc[p] = src[i];
}

// ---- P projection: P[k,h] = sum_j W1[k, h*128+j] * att[h,j]  (fp32) ----
// grid 8 (h), 256 threads: t -> (k = t>>1, src/dst = t&1)
__global__ __launch_bounds__(256) void pa_k(const float* __restrict__ W1,
                                            const float* __restrict__ as1,
                                            const float* __restrict__ ad1,
                                            float* __restrict__ Ps,
                                            float* __restrict__ Pd) {
  int h = blockIdx.x;
  int t = threadIdx.x;
  int k = t >> 1, sd = t & 1;
  const float* att = sd ? ad1 : as1;
  float* P = sd ? Pd : Ps;
  const float* wrow = &W1[(size_t)k * 1024 + h * 128];
  const float* arow = &att[h * 128];
  float s = 0.f;
#pragma unroll 8
  for (int c = 0; c < 128; c++) s += wrow[c] * arow[c];
  P[k * 8 + h] = s;
}

// ---- layer-1 alphas via GEMV: asrc1[n,h] = x[n,:] . Ps[:,h]  (all fp32) ----
__global__ __launch_bounds__(256) void al1_k(const float* __restrict__ x,
                                             const float* __restrict__ Ps,
                                             const float* __restrict__ Pd,
                                             float* __restrict__ asrc,
                                             float* __restrict__ adst, int Nn) {
  __shared__ float ps[1024], pd[1024];
  int t = threadIdx.x;
  for (int i = t; i < 1024; i += 256) { ps[i] = Ps[i]; pd[i] = Pd[i]; }
  __syncthreads();
  int n = blockIdx.x * 256 + t;
  if (n >= Nn) return;
  const float4* xr = (const float4*)&x[(size_t)n * 128];
  float as[8], ad[8];
#pragma unroll
  for (int h = 0; h < 8; h++) { as[h] = 0.f; ad[h] = 0.f; }
  for (int k4 = 0; k4 < 32; k4++) {
    float4 xv = xr[k4];
    float xs[4] = {xv.x, xv.y, xv.z, xv.w};
#pragma unroll
    for (int j = 0; j < 4; j++) {
      int k = k4 * 4 + j;
#pragma unroll
      for (int h = 0; h < 8; h++) {
        as[h] += xs[j] * ps[k * 8 + h];   // LDS uniform addr -> broadcast
        ad[h] += xs[j] * pd[k * 8 + h];
      }
    }
  }
#pragma unroll
  for (int h = 0; h < 8; h++) {
    asrc[n * 8 + h] = as[h];
    adst[n * 8 + h] = ad[h];
  }
}

// ---- layer-1 x-side aggregation (R9 restructure: gather x 256B/edge, not h 2KB) ----
// 1 block = 1 node, 64 threads (2 channels each). Lane l is weight-producer for
// (edge l>>3, head l&7) of each 8-edge batch; consumers shfl. Output
// s[n, h*128 + c] = (sum_e w^h_e x_src[c]) / sum_e w^h_e, rounded to bf16.
__global__ __launch_bounds__(64) void aggx_k(const ushort_t* __restrict__ xb,
                                             const float* __restrict__ asrc,
                                             const float* __restrict__ adst,
                                             const int* __restrict__ offs,
                                             const int* __restrict__ psrc,
                                             ushort_t* __restrict__ sb, int Nn) {
  int n = blockIdx.x;
  int l = threadIdx.x;
  int u_mine = l >> 3, h_mine = l & 7;
  float adn = adst[n * 8 + h_mine];
  int e0 = offs[n], e1 = offs[n + 1];
  int c0 = l * 2;                       // channels 2l, 2l+1
  float acc0[8], acc1[8], wsum[8];
#pragma unroll
  for (int h = 0; h < 8; h++) { acc0[h] = 0.f; acc1[h] = 0.f; wsum[h] = 0.f; }

  for (int i = e0; i < e1; i += 8) {
    int bs = min(8, e1 - i);
    // producer lane: weight for my (edge,head); clamp id for inactive lanes
    int eu = i + (u_mine < bs ? u_mine : bs - 1);
    int se = psrc[eu];
    float v = asrc[se * 8 + h_mine] + adn;   // 8 nodes x 32B contiguous
    v = (v > 0.f) ? v : NEG * v;             // leaky_relu(0.2)
    float wm = __expf(v);                    // hw v_exp_f32
    // gather 8 edges' x chunks (4B each), all in flight
    int ss[8];
    unsigned xvv[8];
#pragma unroll
    for (int u = 0; u < 8; u++) ss[u] = psrc[i + (u < bs ? u : bs - 1)];
#pragma unroll
    for (int u = 0; u < 8; u++) xvv[u] = *(const unsigned*)&xb[(size_t)ss[u] * 128 + c0];
#pragma unroll
    for (int u = 0; u < 8; u++) {
      if (u < bs) {
        union { unsigned u; float f; } a, b;
        a.u = xvv[u] << 16; b.u = xvv[u] & 0xffff0000u;
#pragma unroll
        for (int h = 0; h < 8; h++) {
          float w = __shfl(wm, (u << 3) | h);
          acc0[h] += w * a.f;
          acc1[h] += w * b.f;
          wsum[h] += w;
        }
      }
    }
  }

#pragma unroll
  for (int h = 0; h < 8; h++) {
    float inv = 1.f / wsum[h];
    unsigned pr = (unsigned)f2bf(acc0[h] * inv) | ((unsigned)f2bf(acc1[h] * inv) << 16);
    *(unsigned*)&sb[(size_t)n * 1024 + h * 128 + c0] = pr;  // 64 lanes -> 256B/h contiguous
  }
}

// ---- head-blocked GEMM: g1[n, h*128+j] = elu( s[n,h,:] . W1[:, h*128+j] + b1 ) ----
// blockIdx.x = head (8), blockIdx.y = M-tile. BM=128, BN=128, K=128 (2 k-tiles,
// dbuf GLDS pipeline as mfma_gemm_k). Epilogue: bias+ELU, LDS-staged uint4 store.
__global__ __launch_bounds__(256) void hgemm_k(const ushort_t* __restrict__ S,
                                               const ushort_t* __restrict__ Wt,
                                               const float* __restrict__ bias,
                                               ushort_t* __restrict__ G, int M) {
  __shared__ __attribute__((aligned(16))) ushort_t lds[32768];  // 64KB multi-use
  int tid = threadIdx.x;
  int lane = tid & 63;
  int wave = tid >> 6;
  int wm = (wave >> 1) * 64, wn = (wave & 1) * 64;
  int head = blockIdx.x;
  int hb0 = head * 128;
  int bm = blockIdx.y * 128;
  int lrow = lane & 15, lq = lane >> 4;

  f32x4 acc[4][4];
#pragma unroll
  for (int i = 0; i < 4; i++)
#pragma unroll
    for (int j = 0; j < 4; j++) acc[i][j] = 0.f;

  int srow = lane >> 3;
  int scol = 8 * ((lane & 7) ^ srow);
  const ushort_t* pa[4];
  const ushort_t* pb[4];
  int lofs[4];
#pragma unroll
  for (int c = 0; c < 4; c++) {
    int row = wave * 32 + c * 8 + srow;
    int ga = min(bm + row, M - 1);
    pa[c] = &S[(size_t)ga * 1024 + hb0 + scol];        // A: row stride 1024, head col base
    pb[c] = &Wt[(size_t)(hb0 + row) * 128 + scol];     // B: w1t rows for this head's cols
    lofs[c] = (wave * 4 + c) * 512;
  }

  auto stage = [&](int buf, int k0) {
#pragma unroll
    for (int c = 0; c < 4; c++) GLDS16(pa[c] + k0, &lds[buf * 8192 + lofs[c]]);
#pragma unroll
    for (int c = 0; c < 4; c++) GLDS16(pb[c] + k0, &lds[16384 + buf * 8192 + lofs[c]]);
  };
  auto compute = [&](int buf) {
    const ushort_t* Asb = &lds[buf * 8192];
    const ushort_t* Bsb = &lds[16384 + buf * 8192];
#pragma unroll
    for (int ks = 0; ks < 2; ks++) {
      short8 af[4], bfr[4];
#pragma unroll
      for (int t = 0; t < 4; t++) {
        int cbs = (ks * 64 + lq * 16) ^ ((lrow & 7) << 4);
        af[t]  = *(const short8*)&Asb[(wm + t * 16 + lrow) * 64 + (cbs >> 1)];
        bfr[t] = *(const short8*)&Bsb[(wn + t * 16 + lrow) * 64 + (cbs >> 1)];
      }
#pragma unroll
      for (int i = 0; i < 4; i++)
#pragma unroll
        for (int j = 0; j < 4; j++)
          acc[i][j] = __builtin_amdgcn_mfma_f32_16x16x32_bf16(af[i], bfr[j], acc[i][j], 0, 0, 0);
    }
  };

  stage(0, 0);
  asm volatile("s_waitcnt vmcnt(0)" ::: "memory");
  __builtin_amdgcn_s_barrier();
  stage(1, 64);
  compute(0);
  asm volatile("s_waitcnt vmcnt(0)" ::: "memory");
  __builtin_amdgcn_s_barrier();
  compute(1);

  __syncthreads();  // done reading staging LDS -> alias as C tile

  ushort_t* Cl = lds;  // [128][136]
  float bv[4];
#pragma unroll
  for (int j = 0; j < 4; j++) bv[j] = bias[hb0 + wn + j * 16 + lrow];
#pragma unroll
  for (int i = 0; i < 4; i++) {
#pragma unroll
    for (int j = 0; j < 4; j++) {
      int col = wn + j * 16 + lrow;
#pragma unroll
      for (int r = 0; r < 4; r++) {
        int row = wm + i * 16 + lq * 4 + r;
        Cl[row * 136 + col] = f2bf(elu_f(acc[i][j][r] + bv[j]));
      }
    }
  }
  __syncthreads();
#pragma unroll
  for (int p = 0; p < 8; p++) {
    int row = p * 16 + (tid >> 4);
    int col8 = (tid & 15) * 8;
    if (bm + row < M)
      *(uint4*)&G[(size_t)(bm + row) * 1024 + hb0 + col8] = *(const uint4*)&Cl[row * 136 + col8];
  }
}

// ------- bf16 MFMA GEMM + fused alpha epilogue (layer 2 only) -------
__global__ __launch_bounds__(256) void mfma_gemm_k(const ushort_t* __restrict__ A,
                                                   const ushort_t* __restrict__ Bt,
                                                   ushort_t* __restrict__ Cb,
                                                   const float* __restrict__ att_s,
                                                   const float* __restrict__ att_d,
                                                   float* __restrict__ asrc,
                                                   float* __restrict__ adst,
                                                   int M, int N, int K, int CSHIFT) {
  __shared__ __attribute__((aligned(16))) ushort_t lds[32768];  // 64KB, multi-use
  int tid = threadIdx.x;
  int lane = tid & 63;
  int wave = tid >> 6;
  int wm = (wave >> 1) * 64, wn = (wave & 1) * 64;
  int bm = blockIdx.y * 128, bn = blockIdx.x * 128;
  int lrow = lane & 15, lq = lane >> 4;

  f32x4 acc[4][4];
#pragma unroll
  for (int i = 0; i < 4; i++)
#pragma unroll
    for (int j = 0; j < 4; j++) acc[i][j] = 0.f;

  int srow = lane >> 3;
  int scol = 8 * ((lane & 7) ^ srow);
  const ushort_t* pa[4];
  const ushort_t* pb[4];
  int lofs[4];
#pragma unroll
  for (int c = 0; c < 4; c++) {
    int row = wave * 32 + c * 8 + srow;
    int ga = min(bm + row, M - 1);
    pa[c] = &A[(size_t)ga * K + scol];
    pb[c] = &Bt[(size_t)(bn + row) * K + scol];
    lofs[c] = (wave * 4 + c) * 512;
  }

  auto stage = [&](int buf, int k0) {
#pragma unroll
    for (int c = 0; c < 4; c++) GLDS16(pa[c] + k0, &lds[buf * 8192 + lofs[c]]);
#pragma unroll
    for (int c = 0; c < 4; c++) GLDS16(pb[c] + k0, &lds[16384 + buf * 8192 + lofs[c]]);
  };
  auto compute = [&](int buf) {
    const ushort_t* Asb = &lds[buf * 8192];
    const ushort_t* Bsb = &lds[16384 + buf * 8192];
#pragma unroll
    for (int ks = 0; ks < 2; ks++) {
      short8 af[4], bfr[4];
#pragma unroll
      for (int t = 0; t < 4; t++) {
        int cbs = (ks * 64 + lq * 16) ^ ((lrow & 7) << 4);
        af[t]  = *(const short8*)&Asb[(wm + t * 16 + lrow) * 64 + (cbs >> 1)];
        bfr[t] = *(const short8*)&Bsb[(wn + t * 16 + lrow) * 64 + (cbs >> 1)];
      }
#pragma unroll
      for (int i = 0; i < 4; i++)
#pragma unroll
        for (int j = 0; j < 4; j++)
          acc[i][j] = __builtin_amdgcn_mfma_f32_16x16x32_bf16(af[i], bfr[j], acc[i][j], 0, 0, 0);
    }
  };

  int NT = K >> 6;
  stage(0, 0);
  asm volatile("s_waitcnt vmcnt(0)" ::: "memory");
  __builtin_amdgcn_s_barrier();
  int cur = 0;
  for (int t = 0; t + 1 < NT; ++t) {
    stage(cur ^ 1, (t + 1) << 6);
    compute(cur);
    asm volatile("s_waitcnt vmcnt(0)" ::: "memory");
    __builtin_amdgcn_s_barrier();
    cur ^= 1;
  }
  compute(cur);

  __syncthreads();  // safe to alias staging LDS

  ushort_t* Cl = lds;                       // [128][136]
  float* pls = (float*)&lds[17472];
  float* pld = pls + 256;

  {
    float avs[4], avd[4];
#pragma unroll
    for (int j = 0; j < 4; j++) {
      int col = bn + wn + j * 16 + lrow;
      avs[j] = att_s[col];
      avd[j] = att_d[col];
    }
#pragma unroll
    for (int i = 0; i < 4; i++) {
#pragma unroll
      for (int r = 0; r < 4; r++) {
        float ps = 0.f, pd = 0.f;
#pragma unroll
        for (int j = 0; j < 4; j++) {
          float v = acc[i][j][r];
          ps += v * avs[j];
          pd += v * avd[j];
        }
#pragma unroll
        for (int o = 1; o < 16; o <<= 1) {
          ps += __shfl_xor(ps, o);
          pd += __shfl_xor(pd, o);
        }
        if (lrow == 0) {
          int rr = i * 16 + lq * 4 + r;
          pls[wave * 64 + rr] = ps;
          pld[wave * 64 + rr] = pd;
        }
      }
    }
  }

#pragma unroll
  for (int i = 0; i < 4; i++) {
#pragma unroll
    for (int j = 0; j < 4; j++) {
      int col = wn + j * 16 + lrow;
#pragma unroll
      for (int r = 0; r < 4; r++) {
        int row = wm + i * 16 + lq * 4 + r;
        Cl[row * 136 + col] = f2bf(acc[i][j][r]);
      }
    }
  }
  __syncthreads();

#pragma unroll
  for (int p = 0; p < 8; p++) {
    int row = p * 16 + (tid >> 4);
    int col8 = (tid & 15) * 8;
    if (bm + row < M)
      *(uint4*)&Cb[(size_t)(bm + row) * N + bn + col8] = *(const uint4*)&Cl[row * 136 + col8];
  }

  {
    int r = tid & 127, half = tid >> 7;
    if (bm + r < M) {
      const float* P = half ? pld : pls;
      float* O = half ? adst : asrc;
      int w0 = (r >> 6) * 2, idx = r & 63;
      float va = P[w0 * 64 + idx];
      float vb = P[(w0 + 1) * 64 + idx];
      int h0 = bn >> CSHIFT, h1 = (bn + 64) >> CSHIFT;
      size_t base = (size_t)(bm + r) * HEADS;
      if (h0 == h1) O[base + h0] = va + vb;
      else { O[base + h0] = va; O[base + h1] = vb; }
    }
  }
}

// ---- CSR aggregation (layer 2): depth-2 pipelined gathers + wave alpha sharing ----
template <int F, int CSHIFT, int BT, int NSPLIT, typename OT>
__global__ __launch_bounds__(BT) void aggregate_k(const ushort_t* __restrict__ hb,
                                                  const float* __restrict__ asrc,
                                                  const float* __restrict__ adst,
                                                  const int* __restrict__ offs,
                                                  const int* __restrict__ psrc,
                                                  const float* __restrict__ bias,
                                                  OT* __restrict__ out) {
  constexpr int CPB = F / NSPLIT;
  constexpr int G = (1 << CSHIFT) >> 2;  // threads per head within a wave
  static_assert(CPB == 4 * BT, "CPB/thread mismatch");
  static_assert(G >= 8 && G <= 64, "head group must cover the 8-edge batch");
  int nb = blockIdx.x;
  int n = nb / NSPLIT;
  int coff = (nb - n * NSPLIT) * CPB;
  int t = threadIdx.x;
  int c0 = coff + 4 * t;
  int hh = c0 >> CSHIFT;
  int lane = t & 63;
  int sub = lane & (G - 1);
  int gb = lane & ~(G - 1);
  float adn = adst[n * HEADS + hh];
  int e0 = offs[n], e1 = offs[n + 1];
  float4 acc = make_float4(0.f, 0.f, 0.f, 0.f);
  float wsum = 0.f;

  int i = e0;
  uint2 rA[8];
  float myWA = 0.f;
  bool haveA = (i + 8 <= e1);
  if (haveA) {
    int sA[8];
#pragma unroll
    for (int u = 0; u < 8; u++) sA[u] = psrc[i + u];
#pragma unroll
    for (int u = 0; u < 8; u++) rA[u] = *(const uint2*)&hb[(size_t)sA[u] * F + c0];
    int ms = psrc[i + (sub < 8 ? sub : 0)];
    float v = asrc[ms * HEADS + hh] + adn;
    v = (v > 0.f) ? v : NEG * v;
    myWA = __expf(v);
  }
  while (i + 16 <= e1) {
    int sB[8];
    uint2 rB[8];
#pragma unroll
    for (int u = 0; u < 8; u++) sB[u] = psrc[i + 8 + u];
#pragma unroll
    for (int u = 0; u < 8; u++) rB[u] = *(const uint2*)&hb[(size_t)sB[u] * F + c0];
    int ms = psrc[i + 8 + (sub < 8 ? sub : 0)];
    float vb = asrc[ms * HEADS + hh] + adn;
    vb = (vb > 0.f) ? vb : NEG * vb;
    float myWB = __expf(vb);
#pragma unroll
    for (int u = 0; u < 8; u++) {
      float w = __shfl(myWA, gb + u);
      float4 f = bf4(rA[u]);
      wsum += w;
      acc.x += w * f.x;
      acc.y += w * f.y;
      acc.z += w * f.z;
      acc.w += w * f.w;
    }
    i += 8;
#pragma unroll
    for (int u = 0; u < 8; u++) rA[u] = rB[u];
    myWA = myWB;
  }
  if (haveA) {
#pragma unroll
    for (int u = 0; u < 8; u++) {
      float w = __shfl(myWA, gb + u);
      float4 f = bf4(rA[u]);
      wsum += w;
      acc.x += w * f.x;
      acc.y += w * f.y;
      acc.z += w * f.z;
      acc.w += w * f.w;
    }
    i += 8;
  }
  for (; i < e1; i++) {
    int ss = psrc[i];
    float v = asrc[ss * HEADS + hh] + adn;
    v = (v > 0.f) ? v : NEG * v;
    float w = __expf(v);
    float4 f = bf4(*(const uint2*)&hb[(size_t)ss * F + c0]);
    wsum += w;
    acc.x += w * f.x; acc.y += w * f.y;
    acc.z += w * f.z; acc.w += w * f.w;
  }

  float inv = 1.f / wsum;
  float v0 = elu_f(acc.x * inv + bias[c0]);
  float v1 = elu_f(acc.y * inv + bias[c0 + 1]);
  float v2 = elu_f(acc.z * inv + bias[c0 + 2]);
  float v3 = elu_f(acc.w * inv + bias[c0 + 3]);
  if constexpr (sizeof(OT) == 2) {
    unsigned p0 = (unsigned)f2bf(v0) | ((unsigned)f2bf(v1) << 16);
    unsigned p1 = (unsigned)f2bf(v2) | ((unsigned)f2bf(v3) << 16);
    *(uint2*)&((ushort_t*)out)[(size_t)n * F + c0] = make_uint2(p0, p1);
  } else {
    *(float4*)&((float*)out)[(size_t)n * F + c0] = make_float4(v0, v1, v2, v3);
  }
}

__global__ __launch_bounds__(256) void pool_k(const float* __restrict__ g,
                                              const int* __restrict__ batch,
                                              float* __restrict__ sums, int Nn) {
  int c = blockIdx.x * 256 + threadIdx.x;  // 0..511
  int n0 = blockIdx.y * 50;
  int n1 = min(n0 + 50, Nn);
  if (n0 >= n1) return;
  float acc = 0.f;
  int cur = batch[n0];
  for (int n = n0; n < n1; n++) {
    int b = batch[n];
    if (b != cur) { atomicAdd(&sums[cur * 512 + c], acc); acc = 0.f; cur = b; }
    acc += g[(size_t)n * 512 + c];
  }
  atomicAdd(&sums[cur * 512 + c], acc);
}

// ---------------- mean + fc1(elu) + fc2, one block ----------------
__global__ __launch_bounds__(512) void mlp_k(const float* __restrict__ sums,
                                             const int* __restrict__ bstart,
                                             const int* __restrict__ bend,
                                             const float* __restrict__ w1,
                                             const float* __restrict__ b1,
                                             const float* __restrict__ w2,
                                             const float* __restrict__ b2,
                                             float* __restrict__ out) {
  __shared__ float gm[16 * 512];
  __shared__ float t1[16 * 32];
  int t = threadIdx.x;
  for (int i = t; i < 16 * 512; i += 512) {
    int b = i >> 9;
    float c = (float)(bend[b] - bstart[b]);
    gm[i] = sums[i] / fmaxf(c, 1.f);
  }
  __syncthreads();
  {
    int b = t >> 5, j = t & 31;
    float s = b1[j];
    for (int k = 0; k < 512; k++) s += gm[(b << 9) + k] * w1[k * 32 + j];
    t1[t] = elu_f(s);
  }
  __syncthreads();
  if (t < 160) {
    int b = t / 10, j = t - b * 10;
    float s = b2[j];
#pragma unroll
    for (int k = 0; k < 32; k++) s += t1[b * 32 + k] * w2[k * 10 + j];
    out[t] = s;
  }
}

extern "C" void kernel_launch(void* const* d_in, const int* in_sizes, int n_in,
                              void* d_out, int out_size, void* d_ws, size_t ws_size,
                              hipStream_t stream) {
  const float* x   = (const float*)d_in[0];
  const int*   ei  = (const int*)d_in[1];
  const int* batch = (const int*)d_in[2];
  const float* W1  = (const float*)d_in[3];
  const float* as1 = (const float*)d_in[4];
  const float* ad1 = (const float*)d_in[5];
  const float* b1  = (const float*)d_in[6];
  const float* W2  = (const float*)d_in[7];
  const float* as2 = (const float*)d_in[8];
  const float* ad2 = (const float*)d_in[9];
  const float* b2  = (const float*)d_in[10];
  const float* f1w = (const float*)d_in[11];
  const float* f1b = (const float*)d_in[12];
  const float* f2w = (const float*)d_in[13];
  const float* f2b = (const float*)d_in[14];
  float* out = (float*)d_out;

  const int Nn = in_sizes[2];      // 10000
  const int E = in_sizes[1] / 2;   // 160000
  const int Etot = E + Nn;         // self loops appended

  // ---- workspace layout (4B words, 64-word aligned) ----
  size_t off = 0;
  auto alloc = [&](size_t elems) { size_t o = off; off += (elems + 63) & ~(size_t)63; return o; };
  int* wsi = (int*)d_ws;
  float* wsf = (float*)d_ws;

  size_t o_deg  = alloc(Nn);
  size_t o_pool = alloc(16 * 512);
  size_t zero_words = off;               // only deg+pool accumulate -> zero each call
  size_t o_as1  = alloc((size_t)Nn * 8); // plain-stored (al1_k / GEMM2 epilogue)
  size_t o_ad1  = alloc((size_t)Nn * 8);
  size_t o_as2  = alloc((size_t)Nn * 8);
  size_t o_ad2  = alloc((size_t)Nn * 8);
  size_t o_ps   = alloc(1024);           // P projections [128][8] fp32
  size_t o_pd   = alloc(1024);
  size_t o_bst  = alloc(64);
  size_t o_ben  = alloc(64);
  size_t o_offs = alloc(Nn + 1);
  size_t o_cur  = alloc(Nn);
  size_t o_src  = alloc(Etot);
  size_t o_dst  = alloc(Etot);
  size_t o_psrc = alloc(Etot);
  size_t o_xb   = alloc((size_t)Nn * 128 / 2);   // x bf16  [N,128]
  size_t o_w1t  = alloc(1024 * 128 / 2);         // W1^T bf16 [1024,128]
  size_t o_w2t  = alloc(512 * 1024 / 2);         // W2^T bf16 [512,1024]
  size_t o_s    = alloc((size_t)Nn * 1024 / 2);  // s bf16 [N,1024] (x-side aggregate)
  size_t o_h    = alloc((size_t)Nn * 1024 / 2);  // h2 bf16 [N,512] (layer2 uses first half)
  size_t o_g    = alloc((size_t)Nn * 1024);      // g1 bf16 (first half) then g2 fp32

  ushort_t* xb  = (ushort_t*)(wsi + o_xb);
  ushort_t* w1t = (ushort_t*)(wsi + o_w1t);
  ushort_t* w2t = (ushort_t*)(wsi + o_w2t);
  ushort_t* sb  = (ushort_t*)(wsi + o_s);
  ushort_t* hb  = (ushort_t*)(wsi + o_h);
  ushort_t* g1b = (ushort_t*)(wsi + o_g);

  int eb = (Etot + 255) / 256;

  int nx4 = Nn * 128 / 4;
  int ep_work = (int)((zero_words > (size_t)nx4 ? zero_words : (size_t)nx4));
  int init_blocks = 640 + (ep_work + 255) / 256;
  init_k<<<init_blocks, 256, 0, stream>>>(wsi, (int)zero_words, x, xb,
                                          W1, w1t, W2, w2t, nx4);
  prep_k<<<eb, 256, 0, stream>>>(ei, wsi + o_src, wsi + o_dst, wsi + o_deg,
                                 batch, wsi + o_bst, wsi + o_ben, E, Nn);
  scan_k<<<1, 1024, 0, stream>>>(wsi + o_deg, wsi + o_offs, wsi + o_cur, Nn);
  scatter_k<<<eb, 256, 0, stream>>>(wsi + o_src, wsi + o_dst, wsi + o_cur,
                                    wsi + o_psrc, Etot);

  // ---- layer 1 (restructured): alphas via GEMV; aggregate x; head-blocked GEMM ----
  pa_k<<<8, 256, 0, stream>>>(W1, as1, ad1, wsf + o_ps, wsf + o_pd);
  al1_k<<<(Nn + 255) / 256, 256, 0, stream>>>(x, wsf + o_ps, wsf + o_pd,
                                              wsf + o_as1, wsf + o_ad1, Nn);
  aggx_k<<<Nn, 64, 0, stream>>>(xb, wsf + o_as1, wsf + o_ad1,
                                wsi + o_offs, wsi + o_psrc, sb, Nn);
  hgemm_k<<<dim3(8, (Nn + 127) / 128), 256, 0, stream>>>(sb, w1t, b1, g1b, Nn);

  // ---- layer 2: 1024 -> 8x64 ----
  mfma_gemm_k<<<dim3(512 / 128, (Nn + 127) / 128), 256, 0, stream>>>(
      g1b, w2t, hb, as2, ad2, wsf + o_as2, wsf + o_ad2, Nn, 512, 1024, 6);
  aggregate_k<512, 6, 64, 2, float><<<Nn * 2, 64, 0, stream>>>(
      hb, wsf + o_as2, wsf + o_ad2, wsi + o_offs, wsi + o_psrc, b2, wsf + o_g);

  // ---- pool + MLP ----
  pool_k<<<dim3(2, (Nn + 49) / 50), 256, 0, stream>>>(wsf + o_g, batch, wsf + o_pool, Nn);
  mlp_k<<<1, 512, 0, stream>>>(wsf + o_pool, wsi + o_bst, wsi + o_ben, f1w, f1b, f2w, f2b, out);
}